// Round 5
// baseline (689.002 us; speedup 1.0000x reference)
//
#include <hip/hip_runtime.h>
#include <hip/hip_bf16.h>
#include <math.h>

#define BB 4096
#define HH 4
#define NN 1024
#define DHD 256
#define XLD 1024   // H*DH
#define DECAY 0.99f
#define OMD 0.01f
#define EPSV 1e-5f

typedef __attribute__((ext_vector_type(8))) short bf16x8;
typedef __attribute__((ext_vector_type(4))) float f32x4;
typedef unsigned short u16;

#define MFMA(a, b, c) __builtin_amdgcn_mfma_f32_16x16x32_bf16((a), (b), (c), 0, 0, 0)

static __device__ __forceinline__ u16 f2bf(float x) {
    union { __hip_bfloat16 b; u16 u; } c; c.b = __float2bfloat16(x); return c.u;
}
static __device__ __forceinline__ float bf2f(u16 u) {
    union { __hip_bfloat16 b; u16 u; } c; c.u = u; return __bfloat162float(c.b);
}
static __device__ __forceinline__ void split3(float x, u16& h, u16& m, u16& l) {
    h = f2bf(x);
    float r = x - bf2f(h);
    m = f2bf(r);
    float r2 = r - bf2f(m);
    l = f2bf(r2);
}

// ---------------------------------------------------------------------------
// prep X: Xh2/Xm2/Xl2 = 3-level split(2x) straight; XTh/XTl = 2-level split(x)
// transposed. grid (XLD/64, BB/64)
// ---------------------------------------------------------------------------
__global__ __launch_bounds__(256) void k_prep_x(const float* __restrict__ in,
        u16* __restrict__ xh2, u16* __restrict__ xm2, u16* __restrict__ xl2,
        u16* __restrict__ xth, u16* __restrict__ xtl) {
    __shared__ float T[64][68];
    const int t = threadIdx.x;
    const int c0 = blockIdx.x * 64, i0 = blockIdx.y * 64;
#pragma unroll
    for (int rep = 0; rep < 4; rep++) {
        int id = t + 256 * rep;
        int row = id >> 4, c4 = (id & 15) * 4;
        float4 v = *(const float4*)(in + (size_t)(i0 + row) * XLD + c0 + c4);
        *(float4*)&T[row][c4] = v;
        float xs[4] = {v.x, v.y, v.z, v.w};
        u16 h4[4], m4[4], l4[4];
#pragma unroll
        for (int e = 0; e < 4; e++) split3(2.f * xs[e], h4[e], m4[e], l4[e]);
        size_t o = (size_t)(i0 + row) * XLD + c0 + c4;
        *(ushort4*)(xh2 + o) = make_ushort4(h4[0], h4[1], h4[2], h4[3]);
        *(ushort4*)(xm2 + o) = make_ushort4(m4[0], m4[1], m4[2], m4[3]);
        *(ushort4*)(xl2 + o) = make_ushort4(l4[0], l4[1], l4[2], l4[3]);
    }
    __syncthreads();
    const int or_ = t >> 2, oc = (t & 3) * 16;
    bf16x8 h0, h1, l0, l1;
#pragma unroll
    for (int e = 0; e < 8; e++) {
        float x = T[oc + e][or_];
        u16 h = f2bf(x);
        h0[e] = (short)h; l0[e] = (short)f2bf(x - bf2f(h));
    }
#pragma unroll
    for (int e = 0; e < 8; e++) {
        float x = T[oc + 8 + e][or_];
        u16 h = f2bf(x);
        h1[e] = (short)h; l1[e] = (short)f2bf(x - bf2f(h));
    }
    size_t o = (size_t)(c0 + or_) * BB + i0 + oc;
    *(bf16x8*)(xth + o) = h0;
    *(bf16x8*)(xth + o + 8) = h1;
    *(bf16x8*)(xtl + o) = l0;
    *(bf16x8*)(xtl + o + 8) = l1;
}

// ---------------------------------------------------------------------------
// prep W: 3-level split elementwise (H*N*DH)
// ---------------------------------------------------------------------------
__global__ __launch_bounds__(256) void k_prep_w(const float* __restrict__ w,
        u16* __restrict__ wh, u16* __restrict__ wm, u16* __restrict__ wl) {
    size_t id = ((size_t)blockIdx.x * 256 + threadIdx.x) * 4;
    float4 v = *(const float4*)(w + id);
    float xs[4] = {v.x, v.y, v.z, v.w};
    u16 h4[4], m4[4], l4[4];
#pragma unroll
    for (int e = 0; e < 4; e++) split3(xs[e], h4[e], m4[e], l4[e]);
    *(ushort4*)(wh + id) = make_ushort4(h4[0], h4[1], h4[2], h4[3]);
    *(ushort4*)(wm + id) = make_ushort4(m4[0], m4[1], m4[2], m4[3]);
    *(ushort4*)(wl + id) = make_ushort4(l4[0], l4[1], l4[2], l4[3]);
}

// prep T: 2-level split (H*N*N)
__global__ __launch_bounds__(256) void k_prep_t(const float* __restrict__ w,
        u16* __restrict__ th, u16* __restrict__ tl) {
    size_t id = ((size_t)blockIdx.x * 256 + threadIdx.x) * 4;
    float4 v = *(const float4*)(w + id);
    float xs[4] = {v.x, v.y, v.z, v.w};
    u16 h4[4], l4[4];
#pragma unroll
    for (int e = 0; e < 4; e++) {
        u16 h = f2bf(xs[e]);
        h4[e] = h;
        l4[e] = f2bf(xs[e] - bf2f(h));
    }
    *(ushort4*)(th + id) = make_ushort4(h4[0], h4[1], h4[2], h4[3]);
    *(ushort4*)(tl + id) = make_ushort4(l4[0], l4[1], l4[2], l4[3]);
}

// ---------------------------------------------------------------------------
// wsq[row] = sum_k emb[row][k]^2  (fp32 exact)
// ---------------------------------------------------------------------------
__global__ __launch_bounds__(256) void k_wsq(const float* __restrict__ emb,
                                             float* __restrict__ wsq) {
    int wave = threadIdx.x >> 6;
    int lane = threadIdx.x & 63;
    int row  = blockIdx.x * 4 + wave;
    const float* w = emb + (size_t)row * DHD;
    float4 v = *(const float4*)(w + lane * 4);
    float s = v.x * v.x + v.y * v.y + v.z * v.z + v.w * v.w;
    for (int off = 32; off; off >>= 1) s += __shfl_down(s, off);
    if (lane == 0) wsq[row] = s;
}

// ---------------------------------------------------------------------------
// MFMA logits, high precision (numerics identical to round 4):
//  phase 1: 3-level split of (2x) and w, 6 terms; dominant h*H to fresh acc,
//           VALU-merged. Small terms chain in acc2.
//  phase 2: 2-level split of P and T, 3 terms, chained into acc2 (small mag).
// TILE 64(M=i) x 64(N=j), BK=32. grid (NN/64, BB/64) = 1024 blocks.
// 4 waves: wm=wid>>1, wn=wid&1; each wave owns a 32x32 quadrant (2x2 tiles).
// ---------------------------------------------------------------------------
template <int HASPREV>
__global__ __launch_bounds__(256) void k_logits_mfma(
        const u16* __restrict__ Xh, const u16* __restrict__ Xm, const u16* __restrict__ Xl,
        const u16* __restrict__ Wh, const u16* __restrict__ Wm, const u16* __restrict__ Wl,
        const float* __restrict__ wsq,
        const u16* __restrict__ Ph, const u16* __restrict__ Pl,
        const u16* __restrict__ Th, const u16* __restrict__ Tl,
        float* __restrict__ L) {
    __shared__ u16 Ah[64 * 40], Am[64 * 40], Al[64 * 40];
    __shared__ u16 Bh[64 * 40], Bm[64 * 40], Bl[64 * 40];
    const int t = threadIdx.x;
    const int lane = t & 63, wid = t >> 6;
    const int wmi = wid >> 1, wn = wid & 1;
    const int q = lane >> 4, mr = lane & 15;
    const int j0 = blockIdx.x * 64, i0 = blockIdx.y * 64;
    const int ar = t >> 2, ac = (t & 3) * 8;

    f32x4 zero = {0.f, 0.f, 0.f, 0.f};
    f32x4 s[2][2], acc2[2][2];
#pragma unroll
    for (int mt = 0; mt < 2; mt++)
#pragma unroll
        for (int nt = 0; nt < 2; nt++) { s[mt][nt] = zero; acc2[mt][nt] = zero; }

    // ---- phase 1: split(2x) . split(w), K = DHD ----
    for (int kb = 0; kb < DHD; kb += 32) {
        bf16x8 a0h = *(const bf16x8*)(Xh + (size_t)(i0 + ar) * XLD + kb + ac);
        bf16x8 a0m = *(const bf16x8*)(Xm + (size_t)(i0 + ar) * XLD + kb + ac);
        bf16x8 a0l = *(const bf16x8*)(Xl + (size_t)(i0 + ar) * XLD + kb + ac);
        bf16x8 b0h = *(const bf16x8*)(Wh + (size_t)(j0 + ar) * DHD + kb + ac);
        bf16x8 b0m = *(const bf16x8*)(Wm + (size_t)(j0 + ar) * DHD + kb + ac);
        bf16x8 b0l = *(const bf16x8*)(Wl + (size_t)(j0 + ar) * DHD + kb + ac);
        __syncthreads();
        *(bf16x8*)&Ah[ar * 40 + ac] = a0h;
        *(bf16x8*)&Am[ar * 40 + ac] = a0m;
        *(bf16x8*)&Al[ar * 40 + ac] = a0l;
        *(bf16x8*)&Bh[ar * 40 + ac] = b0h;
        *(bf16x8*)&Bm[ar * 40 + ac] = b0m;
        *(bf16x8*)&Bl[ar * 40 + ac] = b0l;
        __syncthreads();
        bf16x8 afh[2], afm[2], afl[2], bfh[2], bfm[2], bfl[2];
#pragma unroll
        for (int mt = 0; mt < 2; mt++) {
            int row = (wmi * 32 + mt * 16 + mr) * 40 + q * 8;
            afh[mt] = *(const bf16x8*)&Ah[row];
            afm[mt] = *(const bf16x8*)&Am[row];
            afl[mt] = *(const bf16x8*)&Al[row];
        }
#pragma unroll
        for (int nt = 0; nt < 2; nt++) {
            int row = (wn * 32 + nt * 16 + mr) * 40 + q * 8;
            bfh[nt] = *(const bf16x8*)&Bh[row];
            bfm[nt] = *(const bf16x8*)&Bm[row];
            bfl[nt] = *(const bf16x8*)&Bl[row];
        }
#pragma unroll
        for (int mt = 0; mt < 2; mt++)
#pragma unroll
            for (int nt = 0; nt < 2; nt++) {
                f32x4 fresh = MFMA(afh[mt], bfh[nt], zero);   // dominant term
                s[mt][nt] += fresh;                           // VALU merge
                acc2[mt][nt] = MFMA(afh[mt], bfm[nt], acc2[mt][nt]);
                acc2[mt][nt] = MFMA(afm[mt], bfh[nt], acc2[mt][nt]);
                acc2[mt][nt] = MFMA(afh[mt], bfl[nt], acc2[mt][nt]);
                acc2[mt][nt] = MFMA(afm[mt], bfm[nt], acc2[mt][nt]);
                acc2[mt][nt] = MFMA(afl[mt], bfh[nt], acc2[mt][nt]);
            }
    }

    // ---- phase 2: split(P) . split(T)^T, K = NN, into small accumulator ----
    if (HASPREV) {
        for (int kb = 0; kb < NN; kb += 32) {
            bf16x8 a0h = *(const bf16x8*)(Ph + (size_t)(i0 + ar) * NN + kb + ac);
            bf16x8 a0l = *(const bf16x8*)(Pl + (size_t)(i0 + ar) * NN + kb + ac);
            bf16x8 b0h = *(const bf16x8*)(Th + (size_t)(j0 + ar) * NN + kb + ac);
            bf16x8 b0l = *(const bf16x8*)(Tl + (size_t)(j0 + ar) * NN + kb + ac);
            __syncthreads();
            *(bf16x8*)&Ah[ar * 40 + ac] = a0h;
            *(bf16x8*)&Al[ar * 40 + ac] = a0l;
            *(bf16x8*)&Bh[ar * 40 + ac] = b0h;
            *(bf16x8*)&Bl[ar * 40 + ac] = b0l;
            __syncthreads();
            bf16x8 afh[2], afl[2], bfh[2], bfl[2];
#pragma unroll
            for (int mt = 0; mt < 2; mt++) {
                int row = (wmi * 32 + mt * 16 + mr) * 40 + q * 8;
                afh[mt] = *(const bf16x8*)&Ah[row];
                afl[mt] = *(const bf16x8*)&Al[row];
            }
#pragma unroll
            for (int nt = 0; nt < 2; nt++) {
                int row = (wn * 32 + nt * 16 + mr) * 40 + q * 8;
                bfh[nt] = *(const bf16x8*)&Bh[row];
                bfl[nt] = *(const bf16x8*)&Bl[row];
            }
#pragma unroll
            for (int mt = 0; mt < 2; mt++)
#pragma unroll
                for (int nt = 0; nt < 2; nt++) {
                    acc2[mt][nt] = MFMA(afh[mt], bfh[nt], acc2[mt][nt]);
                    acc2[mt][nt] = MFMA(afh[mt], bfl[nt], acc2[mt][nt]);
                    acc2[mt][nt] = MFMA(afl[mt], bfh[nt], acc2[mt][nt]);
                }
        }
    }

    float wq[2];
#pragma unroll
    for (int nt = 0; nt < 2; nt++) wq[nt] = wsq[j0 + wn * 32 + nt * 16 + mr];
#pragma unroll
    for (int mt = 0; mt < 2; mt++)
#pragma unroll
        for (int nt = 0; nt < 2; nt++)
#pragma unroll
            for (int r = 0; r < 4; r++) {
                int gi = i0 + wmi * 32 + mt * 16 + q * 4 + r;
                int gj = j0 + wn * 32 + nt * 16 + mr;
                L[(size_t)gi * NN + gj] = (s[mt][nt][r] + acc2[mt][nt][r]) - wq[nt];
            }
}

// ---------------------------------------------------------------------------
// softmax row of N=1024, argmax -> codes, writes split-bf16 probs
// ---------------------------------------------------------------------------
__global__ __launch_bounds__(256) void k_softmax(const float* __restrict__ L,
                                                 u16* __restrict__ Ph,
                                                 u16* __restrict__ Pl,
                                                 float* __restrict__ codes,
                                                 int h) {
    __shared__ float smax[256];
    __shared__ int   sidx[256];
    const int i = blockIdx.x;
    const int t = threadIdx.x;
    const float* row = L + (size_t)i * NN;

    float v[4];
    float m = -INFINITY;
    int   mi = 0;
#pragma unroll
    for (int q4 = 0; q4 < 4; q4++) {
        int j = q4 * 256 + t;
        v[q4] = row[j];
        if (v[q4] > m) { m = v[q4]; mi = j; }
    }
    smax[t] = m; sidx[t] = mi;
    __syncthreads();
    for (int s = 128; s; s >>= 1) {
        if (t < s) {
            float o = smax[t + s]; int oi = sidx[t + s];
            if (o > smax[t] || (o == smax[t] && oi < sidx[t])) { smax[t] = o; sidx[t] = oi; }
        }
        __syncthreads();
    }
    m = smax[0];
    int code = sidx[0];
    __syncthreads();

    float s = 0.f;
#pragma unroll
    for (int q4 = 0; q4 < 4; q4++) { v[q4] = expf(v[q4] - m); s += v[q4]; }
    smax[t] = s;
    __syncthreads();
    for (int ss = 128; ss; ss >>= 1) {
        if (t < ss) smax[t] += smax[t + ss];
        __syncthreads();
    }
    float inv = 1.0f / smax[0];
#pragma unroll
    for (int q4 = 0; q4 < 4; q4++) {
        float pv = v[q4] * inv;
        u16 hb = f2bf(pv);
        Ph[(size_t)i * NN + q4 * 256 + t] = hb;
        Pl[(size_t)i * NN + q4 * 256 + t] = f2bf(pv - bf2f(hb));
    }
    if (t == 0) codes[(size_t)i * HH + h] = (float)code;
}

// ---------------------------------------------------------------------------
// transpose Phi/Plo (B x N) -> PThi/PTlo (N x B). grid (NN/64, BB/64)
// ---------------------------------------------------------------------------
__global__ __launch_bounds__(256) void k_transposeP(const u16* __restrict__ Ph,
        const u16* __restrict__ Pl, u16* __restrict__ PTh, u16* __restrict__ PTl) {
    __shared__ u16 U[64][72];
    const int t = threadIdx.x;
    const int j0 = blockIdx.x * 64, i0 = blockIdx.y * 64;
    for (int pass = 0; pass < 2; pass++) {
        const u16* src = pass ? Pl : Ph;
        u16* dst = pass ? PTl : PTh;
        if (pass) __syncthreads();
#pragma unroll
        for (int rep = 0; rep < 2; rep++) {
            int id = t + 256 * rep;
            int row = id >> 3, c8 = (id & 7) * 8;
            *(bf16x8*)&U[row][c8] = *(const bf16x8*)(src + (size_t)(i0 + row) * NN + j0 + c8);
        }
        __syncthreads();
        int or_ = t >> 2, oc = (t & 3) * 16;
        bf16x8 v0, v1;
#pragma unroll
        for (int e = 0; e < 8; e++) v0[e] = (short)U[oc + e][or_];
#pragma unroll
        for (int e = 0; e < 8; e++) v1[e] = (short)U[oc + 8 + e][or_];
        size_t o = (size_t)(j0 + or_) * BB + i0 + oc;
        *(bf16x8*)(dst + o) = v0;
        *(bf16x8*)(dst + o + 8) = v1;
    }
}

// ---------------------------------------------------------------------------
// colsum[j] += slab sum of (Phi+Plo)
// ---------------------------------------------------------------------------
__global__ __launch_bounds__(256) void k_colsum(const u16* __restrict__ Ph,
                                                const u16* __restrict__ Pl,
                                                float* __restrict__ colsum) {
    int j  = blockIdx.x * 256 + threadIdx.x;
    int i0 = blockIdx.y * 256;
    float s = 0.f;
    for (int i = i0; i < i0 + 256; i++)
        s += bf2f(Ph[(size_t)i * NN + j]) + bf2f(Pl[(size_t)i * NN + j]);
    atomicAdd(&colsum[j], s);
}

// ---------------------------------------------------------------------------
// csn[j] = (cs[j]+eps)/(n+N*eps)*n
// ---------------------------------------------------------------------------
__global__ __launch_bounds__(1024) void k_cs(const float* __restrict__ cluster_size,
                                             const float* __restrict__ colsum,
                                             float* __restrict__ csn, int h) {
    __shared__ float red[1024];
    int j = threadIdx.x;
    float cs = cluster_size[h * NN + j] * DECAY + OMD * colsum[j];
    red[j] = cs;
    __syncthreads();
    for (int s = 512; s; s >>= 1) {
        if (j < s) red[j] += red[j + s];
        __syncthreads();
    }
    float n = red[0];
    csn[j] = (cs + EPSV) / (n + NN * EPSV) * n;
}

// ---------------------------------------------------------------------------
// dw partial: dw[j][kd] = sum_i P[i][j]*X[i][kd] via PT (A) x XT (B), split x split.
// TILE 64(M=j) x 64(N=kd). grid (DHD/64, NN/64, 16 i-slabs of 256) = 1024 blocks
// ---------------------------------------------------------------------------
__global__ __launch_bounds__(256) void k_dw(
        const u16* __restrict__ PTh, const u16* __restrict__ PTl,  // [N][B]
        const u16* __restrict__ XTh, const u16* __restrict__ XTl,  // head [DH][B]
        float* __restrict__ partial) {                             // [N][DH]
    __shared__ u16 Ah[64 * 40], Al[64 * 40], Bh[64 * 40], Bl[64 * 40];
    const int t = threadIdx.x;
    const int lane = t & 63, wid = t >> 6;
    const int wmi = wid >> 1, wn = wid & 1;
    const int q = lane >> 4, mr = lane & 15;
    const int kd0 = blockIdx.x * 64, j0 = blockIdx.y * 64;
    const int ibeg = blockIdx.z * 256;
    const int ar = t >> 2, ac = (t & 3) * 8;

    f32x4 zero = {0.f, 0.f, 0.f, 0.f};
    f32x4 acc[2][2];
#pragma unroll
    for (int mt = 0; mt < 2; mt++)
#pragma unroll
        for (int nt = 0; nt < 2; nt++) acc[mt][nt] = zero;

    for (int ib = ibeg; ib < ibeg + 256; ib += 32) {
        bf16x8 a0h = *(const bf16x8*)(PTh + (size_t)(j0 + ar) * BB + ib + ac);
        bf16x8 a0l = *(const bf16x8*)(PTl + (size_t)(j0 + ar) * BB + ib + ac);
        bf16x8 b0h = *(const bf16x8*)(XTh + (size_t)(kd0 + ar) * BB + ib + ac);
        bf16x8 b0l = *(const bf16x8*)(XTl + (size_t)(kd0 + ar) * BB + ib + ac);
        __syncthreads();
        *(bf16x8*)&Ah[ar * 40 + ac] = a0h;
        *(bf16x8*)&Al[ar * 40 + ac] = a0l;
        *(bf16x8*)&Bh[ar * 40 + ac] = b0h;
        *(bf16x8*)&Bl[ar * 40 + ac] = b0l;
        __syncthreads();
        bf16x8 afh[2], afl[2], bfh[2], bfl[2];
#pragma unroll
        for (int mt = 0; mt < 2; mt++) {
            int row = (wmi * 32 + mt * 16 + mr) * 40 + q * 8;
            afh[mt] = *(const bf16x8*)&Ah[row];
            afl[mt] = *(const bf16x8*)&Al[row];
        }
#pragma unroll
        for (int nt = 0; nt < 2; nt++) {
            int row = (wn * 32 + nt * 16 + mr) * 40 + q * 8;
            bfh[nt] = *(const bf16x8*)&Bh[row];
            bfl[nt] = *(const bf16x8*)&Bl[row];
        }
#pragma unroll
        for (int mt = 0; mt < 2; mt++)
#pragma unroll
            for (int nt = 0; nt < 2; nt++) {
                acc[mt][nt] = MFMA(afh[mt], bfh[nt], acc[mt][nt]);
                acc[mt][nt] = MFMA(afh[mt], bfl[nt], acc[mt][nt]);
                acc[mt][nt] = MFMA(afl[mt], bfh[nt], acc[mt][nt]);
            }
    }
#pragma unroll
    for (int mt = 0; mt < 2; mt++)
#pragma unroll
        for (int nt = 0; nt < 2; nt++)
#pragma unroll
            for (int r = 0; r < 4; r++) {
                int gj = j0 + wmi * 32 + mt * 16 + q * 4 + r;
                int gk = kd0 + wn * 32 + nt * 16 + mr;
                atomicAdd(&partial[(size_t)gj * DHD + gk], acc[mt][nt][r]);
            }
}

// ---------------------------------------------------------------------------
// neww epilogue + transpose: NWT[kd][j] = split((ema*DECAY + OMD*partial)/csn[j])
// grid (NN/64, DHD/64)
// ---------------------------------------------------------------------------
__global__ __launch_bounds__(256) void k_neww_ep(const float* __restrict__ partial,
        const float* __restrict__ ema, const float* __restrict__ csn,
        u16* __restrict__ NWh, u16* __restrict__ NWl) {
    __shared__ float T[64][68];
    const int t = threadIdx.x;
    const int j0 = blockIdx.x * 64, kd0 = blockIdx.y * 64;
#pragma unroll
    for (int rep = 0; rep < 4; rep++) {
        int id = t + 256 * rep;
        int jr = id >> 4, c4 = (id & 15) * 4;
        float4 pp = *(const float4*)(partial + (size_t)(j0 + jr) * DHD + kd0 + c4);
        float4 ee = *(const float4*)(ema + (size_t)(j0 + jr) * DHD + kd0 + c4);
        float ic = 1.0f / csn[j0 + jr];
        float4 v;
        v.x = (ee.x * DECAY + OMD * pp.x) * ic;
        v.y = (ee.y * DECAY + OMD * pp.y) * ic;
        v.z = (ee.z * DECAY + OMD * pp.z) * ic;
        v.w = (ee.w * DECAY + OMD * pp.w) * ic;
        *(float4*)&T[jr][c4] = v;
    }
    __syncthreads();
    const int or_ = t >> 2, oc = (t & 3) * 16;
    bf16x8 h0, h1, l0, l1;
#pragma unroll
    for (int e = 0; e < 8; e++) {
        float x = T[oc + e][or_];
        u16 h = f2bf(x);
        h0[e] = (short)h; l0[e] = (short)f2bf(x - bf2f(h));
    }
#pragma unroll
    for (int e = 0; e < 8; e++) {
        float x = T[oc + 8 + e][or_];
        u16 h = f2bf(x);
        h1[e] = (short)h; l1[e] = (short)f2bf(x - bf2f(h));
    }
    size_t o = (size_t)(kd0 + or_) * NN + j0 + oc;
    *(bf16x8*)(NWh + o) = h0;
    *(bf16x8*)(NWh + o + 8) = h1;
    *(bf16x8*)(NWl + o) = l0;
    *(bf16x8*)(NWl + o + 8) = l1;
}

// ---------------------------------------------------------------------------
// quant: q[i][kd] += sum_j P[i][j]*NW[j][kd] via P (A) x NWT (B), split x split.
// TILE 64(M=i) x 64(N=kd). grid (DHD/64, BB/64, 4 j-slabs of 256) = 1024 blocks
// ---------------------------------------------------------------------------
__global__ __launch_bounds__(256) void k_quant(
        const u16* __restrict__ Ph, const u16* __restrict__ Pl,    // [B][N]
        const u16* __restrict__ NWh, const u16* __restrict__ NWl,  // [DH][N]
        float* __restrict__ outq, int h) {                         // [B][XLD]
    __shared__ u16 Ah[64 * 40], Al[64 * 40], Bh[64 * 40], Bl[64 * 40];
    const int t = threadIdx.x;
    const int lane = t & 63, wid = t >> 6;
    const int wmi = wid >> 1, wn = wid & 1;
    const int q = lane >> 4, mr = lane & 15;
    const int kd0 = blockIdx.x * 64, i0 = blockIdx.y * 64;
    const int jbeg = blockIdx.z * 256;
    const int ar = t >> 2, ac = (t & 3) * 8;

    f32x4 zero = {0.f, 0.f, 0.f, 0.f};
    f32x4 acc[2][2];
#pragma unroll
    for (int mt = 0; mt < 2; mt++)
#pragma unroll
        for (int nt = 0; nt < 2; nt++) acc[mt][nt] = zero;

    for (int jb = jbeg; jb < jbeg + 256; jb += 32) {
        bf16x8 a0h = *(const bf16x8*)(Ph + (size_t)(i0 + ar) * NN + jb + ac);
        bf16x8 a0l = *(const bf16x8*)(Pl + (size_t)(i0 + ar) * NN + jb + ac);
        bf16x8 b0h = *(const bf16x8*)(NWh + (size_t)(kd0 + ar) * NN + jb + ac);
        bf16x8 b0l = *(const bf16x8*)(NWl + (size_t)(kd0 + ar) * NN + jb + ac);
        __syncthreads();
        *(bf16x8*)&Ah[ar * 40 + ac] = a0h;
        *(bf16x8*)&Al[ar * 40 + ac] = a0l;
        *(bf16x8*)&Bh[ar * 40 + ac] = b0h;
        *(bf16x8*)&Bl[ar * 40 + ac] = b0l;
        __syncthreads();
        bf16x8 afh[2], afl[2], bfh[2], bfl[2];
#pragma unroll
        for (int mt = 0; mt < 2; mt++) {
            int row = (wmi * 32 + mt * 16 + mr) * 40 + q * 8;
            afh[mt] = *(const bf16x8*)&Ah[row];
            afl[mt] = *(const bf16x8*)&Al[row];
        }
#pragma unroll
        for (int nt = 0; nt < 2; nt++) {
            int row = (wn * 32 + nt * 16 + mr) * 40 + q * 8;
            bfh[nt] = *(const bf16x8*)&Bh[row];
            bfl[nt] = *(const bf16x8*)&Bl[row];
        }
#pragma unroll
        for (int mt = 0; mt < 2; mt++)
#pragma unroll
            for (int nt = 0; nt < 2; nt++) {
                acc[mt][nt] = MFMA(afh[mt], bfh[nt], acc[mt][nt]);
                acc[mt][nt] = MFMA(afh[mt], bfl[nt], acc[mt][nt]);
                acc[mt][nt] = MFMA(afl[mt], bfh[nt], acc[mt][nt]);
            }
    }
#pragma unroll
    for (int mt = 0; mt < 2; mt++)
#pragma unroll
        for (int nt = 0; nt < 2; nt++)
#pragma unroll
            for (int r = 0; r < 4; r++) {
                int gi = i0 + wmi * 32 + mt * 16 + q * 4 + r;
                int gk = kd0 + wn * 32 + nt * 16 + mr;
                atomicAdd(&outq[(size_t)gi * XLD + h * DHD + gk], acc[mt][nt][r]);
            }
}

// ---------------------------------------------------------------------------
// loss[i] = 1.25 * mean_k (q[i][k] - x[i][k])^2
// ---------------------------------------------------------------------------
__global__ __launch_bounds__(256) void k_loss(const float* __restrict__ x,
                                              const float* __restrict__ qv,
                                              float* __restrict__ loss) {
    __shared__ float red[256];
    const int i = blockIdx.x, t = threadIdx.x;
    const float* xr = x + (size_t)i * XLD;
    const float* qr = qv + (size_t)i * XLD;
    float s = 0.f;
#pragma unroll
    for (int q4 = 0; q4 < 4; q4++) {
        int k = q4 * 256 + t;
        float d = qr[k] - xr[k];
        s += d * d;
    }
    red[t] = s;
    __syncthreads();
    for (int ss = 128; ss; ss >>= 1) {
        if (t < ss) red[t] += red[t + ss];
        __syncthreads();
    }
    if (t == 0) loss[i] = 1.25f * red[0] * (1.0f / 1024.0f);
}

// ---------------------------------------------------------------------------
extern "C" void kernel_launch(void* const* d_in, const int* in_sizes, int n_in,
                              void* d_out, int out_size, void* d_ws, size_t ws_size,
                              hipStream_t stream) {
    const float* inputs = (const float*)d_in[0];
    const float* emb    = (const float*)d_in[1];
    const float* ema    = (const float*)d_in[2];
    const float* csz    = (const float*)d_in[3];
    const float* trans  = (const float*)d_in[4];

    float* out   = (float*)d_out;
    float* loss  = out;
    float* quant = out + BB;
    float* codes = out + BB + (size_t)BB * XLD;

    char* p = (char*)d_ws;
    float* L = (float*)p; p += (size_t)BB * NN * 4;   // 16MB; PT aliased here
    u16* PTh = (u16*)L;
    u16* PTl = PTh + (size_t)BB * NN;
    u16* Ph  = (u16*)p; p += (size_t)BB * NN * 2;
    u16* Pl  = (u16*)p; p += (size_t)BB * NN * 2;
    u16* Xh2 = (u16*)p; p += (size_t)BB * XLD * 2;
    u16* Xm2 = (u16*)p; p += (size_t)BB * XLD * 2;
    u16* Xl2 = (u16*)p; p += (size_t)BB * XLD * 2;
    u16* XTh = (u16*)p; p += (size_t)XLD * BB * 2;
    u16* XTl = (u16*)p; p += (size_t)XLD * BB * 2;
    u16* Wh  = (u16*)p; p += (size_t)HH * NN * DHD * 2;
    u16* Wm  = (u16*)p; p += (size_t)HH * NN * DHD * 2;
    u16* Wl  = (u16*)p; p += (size_t)HH * NN * DHD * 2;
    u16* Th  = (u16*)p; p += (size_t)HH * NN * NN * 2;
    u16* Tl  = (u16*)p; p += (size_t)HH * NN * NN * 2;
    u16* NWh = (u16*)p; p += (size_t)DHD * NN * 2;
    u16* NWl = (u16*)p; p += (size_t)DHD * NN * 2;
    float* wsq    = (float*)p; p += (size_t)HH * NN * 4;
    float* colsum = (float*)p; p += NN * 4;
    float* csn    = (float*)p; p += NN * 4;
    float* partial = (float*)p; p += (size_t)NN * DHD * 4;

    k_prep_x<<<dim3(XLD / 64, BB / 64), 256, 0, stream>>>(inputs, Xh2, Xm2, Xl2, XTh, XTl);
    k_prep_w<<<HH * NN * DHD / 1024, 256, 0, stream>>>(emb, Wh, Wm, Wl);
    k_prep_t<<<HH * NN * NN / 1024, 256, 0, stream>>>(trans, Th, Tl);
    k_wsq<<<HH * NN / 4, 256, 0, stream>>>(emb, wsq);
    hipMemsetAsync(quant, 0, (size_t)BB * XLD * 4, stream);

    for (int h = 0; h < HH; h++) {
        const u16* Xhh = Xh2 + h * DHD;
        const u16* Xmh = Xm2 + h * DHD;
        const u16* Xlh = Xl2 + h * DHD;
        const u16* Whh = Wh + (size_t)h * NN * DHD;
        const u16* Wmh = Wm + (size_t)h * NN * DHD;
        const u16* Wlh = Wl + (size_t)h * NN * DHD;
        if (h == 0)
            k_logits_mfma<0><<<dim3(NN / 64, BB / 64), 256, 0, stream>>>(
                Xhh, Xmh, Xlh, Whh, Wmh, Wlh, wsq + h * NN,
                nullptr, nullptr, nullptr, nullptr, L);
        else
            k_logits_mfma<1><<<dim3(NN / 64, BB / 64), 256, 0, stream>>>(
                Xhh, Xmh, Xlh, Whh, Wmh, Wlh, wsq + h * NN,
                Ph, Pl, Th + (size_t)h * NN * NN, Tl + (size_t)h * NN * NN, L);

        k_softmax<<<BB, 256, 0, stream>>>(L, Ph, Pl, codes, h);
        k_transposeP<<<dim3(NN / 64, BB / 64), 256, 0, stream>>>(Ph, Pl, PTh, PTl);

        hipMemsetAsync(colsum, 0, NN * sizeof(float), stream);
        k_colsum<<<dim3(NN / 256, 16), 256, 0, stream>>>(Ph, Pl, colsum);
        k_cs<<<1, NN, 0, stream>>>(csz, colsum, csn, h);

        hipMemsetAsync(partial, 0, (size_t)NN * DHD * sizeof(float), stream);
        k_dw<<<dim3(DHD / 64, NN / 64, 16), 256, 0, stream>>>(
            PTh, PTl, XTh + (size_t)h * DHD * BB, XTl + (size_t)h * DHD * BB, partial);
        k_neww_ep<<<dim3(NN / 64, DHD / 64), 256, 0, stream>>>(
            partial, ema + (size_t)h * NN * DHD, csn, NWh, NWl);

        k_quant<<<dim3(DHD / 64, BB / 64, 4), 256, 0, stream>>>(
            Ph, Pl, NWh, NWl, quant, h);
    }

    k_loss<<<BB, 256, 0, stream>>>(inputs, quant, loss);
}

// Round 6
// 669.591 us; speedup vs baseline: 1.0290x; 1.0290x over previous
//
#include <hip/hip_runtime.h>
#include <hip/hip_bf16.h>
#include <math.h>

#define BB 4096
#define HH 4
#define NN 1024
#define DHD 256
#define XLD 1024   // H*DH
#define DECAY 0.99f
#define OMD 0.01f
#define EPSV 1e-5f

typedef __attribute__((ext_vector_type(8))) short bf16x8;
typedef __attribute__((ext_vector_type(4))) float f32x4;
typedef unsigned short u16;

#define MFMA(a, b, c) __builtin_amdgcn_mfma_f32_16x16x32_bf16((a), (b), (c), 0, 0, 0)

// Fragment-packed layout: matrix [R][K] -> tiles (rt = r>>4, kt = k>>5), frag of
// 512 u16 at ((rt*TK + kt)*512); within frag, lane = (r&15) | (((k>>3)&3)<<4)
// holds elements k = kt*32 + (lane>>4)*8 + j, j=0..7 at offset lane*8+j.
// A wave loads its 16x32 fragment with ONE 16B load at frag_base + lane*8.

static __device__ __forceinline__ u16 f2bf(float x) {
    union { __hip_bfloat16 b; u16 u; } c; c.b = __float2bfloat16(x); return c.u;
}
static __device__ __forceinline__ float bf2f(u16 u) {
    union { __hip_bfloat16 b; u16 u; } c; c.u = u; return __bfloat162float(c.b);
}
static __device__ __forceinline__ void split3(float x, u16& h, u16& m, u16& l) {
    h = f2bf(x);
    float r = x - bf2f(h);
    m = f2bf(r);
    float r2 = r - bf2f(m);
    l = f2bf(r2);
}

// ---------------------------------------------------------------------------
// prep X: Xp (3-level split of 2x, A-layout per head: rows=B, K=DHD, TK=8) and
// XTp (2-level split of x, B-layout per head: rows=DHD, K=B, TK=128).
// grid (XLD/64, BB/64).
// ---------------------------------------------------------------------------
__global__ __launch_bounds__(256) void k_prep_x(const float* __restrict__ in,
        u16* __restrict__ xph, u16* __restrict__ xpm, u16* __restrict__ xpl,
        u16* __restrict__ xtph, u16* __restrict__ xtpl) {
    __shared__ float T[64][68];
    const int t = threadIdx.x, lane = t & 63, wid = t >> 6;
    const int q = lane >> 4, mr = lane & 15;
    const int c0 = blockIdx.x * 64, i0 = blockIdx.y * 64;
    const int h = c0 >> 8, kl0 = c0 & 255;
#pragma unroll
    for (int rep = 0; rep < 4; rep++) {
        int id = t + 256 * rep;
        int row = id >> 4, c4 = (id & 15) * 4;
        float4 v = *(const float4*)(in + (size_t)(i0 + row) * XLD + c0 + c4);
        *(float4*)&T[row][c4] = v;
    }
    __syncthreads();
    // Xp: 8 frags/level in this block (4 row-tiles x 2 k-tiles)
    for (int f = wid; f < 8; f += 4) {
        int a = f >> 1, b = f & 1;
        bf16x8 vh, vm, vl;
#pragma unroll
        for (int e = 0; e < 8; e++) {
            float x2 = 2.f * T[16 * a + mr][b * 32 + q * 8 + e];
            u16 hh, mm, ll; split3(x2, hh, mm, ll);
            vh[e] = (short)hh; vm[e] = (short)mm; vl[e] = (short)ll;
        }
        size_t o = (size_t)h * BB * DHD +
                   ((size_t)((i0 >> 4) + a) * 8 + ((kl0 >> 5) + b)) * 512 + lane * 8;
        *(bf16x8*)(xph + o) = vh;
        *(bf16x8*)(xpm + o) = vm;
        *(bf16x8*)(xpl + o) = vl;
    }
    // XTp: rows = kd (local col), K = i
    for (int f = wid; f < 8; f += 4) {
        int a = f >> 1, b = f & 1;
        bf16x8 vh, vl;
#pragma unroll
        for (int e = 0; e < 8; e++) {
            float x = T[b * 32 + q * 8 + e][16 * a + mr];
            u16 hh = f2bf(x);
            u16 ll = f2bf(x - bf2f(hh));
            vh[e] = (short)hh; vl[e] = (short)ll;
        }
        size_t o = (size_t)h * DHD * BB +
                   ((size_t)((kl0 >> 4) + a) * 128 + ((i0 >> 5) + b)) * 512 + lane * 8;
        *(bf16x8*)(xtph + o) = vh;
        *(bf16x8*)(xtpl + o) = vl;
    }
}

// ---------------------------------------------------------------------------
// prep W: 3-level split, B-layout per head (rows=N, K=DHD, TK=8). grid 512.
// ---------------------------------------------------------------------------
__global__ __launch_bounds__(256) void k_prep_w(const float* __restrict__ w,
        u16* __restrict__ wph, u16* __restrict__ wpm, u16* __restrict__ wpl) {
    const int t = threadIdx.x, lane = t & 63, wid = t >> 6;
    const int q = lane >> 4, mr = lane & 15;
    int fid = blockIdx.x * 4 + wid;
    int kt = fid & 7, jt = (fid >> 3) & 63, h = fid >> 9;
    const float* src = w + (size_t)(h * NN + jt * 16 + mr) * DHD + kt * 32 + q * 8;
    bf16x8 vh, vm, vl;
#pragma unroll
    for (int e = 0; e < 8; e++) {
        u16 hh, mm, ll; split3(src[e], hh, mm, ll);
        vh[e] = (short)hh; vm[e] = (short)mm; vl[e] = (short)ll;
    }
    size_t o = (size_t)h * NN * DHD + ((size_t)jt * 8 + kt) * 512 + lane * 8;
    *(bf16x8*)(wph + o) = vh;
    *(bf16x8*)(wpm + o) = vm;
    *(bf16x8*)(wpl + o) = vl;
}

// prep T: 2-level split, B-layout per head (rows=N, K=N, TK=32). grid 2048.
__global__ __launch_bounds__(256) void k_prep_t(const float* __restrict__ w,
        u16* __restrict__ tph, u16* __restrict__ tpl) {
    const int t = threadIdx.x, lane = t & 63, wid = t >> 6;
    const int q = lane >> 4, mr = lane & 15;
    int fid = blockIdx.x * 4 + wid;
    int kt = fid & 31, jt = (fid >> 5) & 63, h = fid >> 11;
    const float* src = w + (size_t)(h * NN + jt * 16 + mr) * NN + kt * 32 + q * 8;
    bf16x8 vh, vl;
#pragma unroll
    for (int e = 0; e < 8; e++) {
        u16 hh = f2bf(src[e]);
        u16 ll = f2bf(src[e] - bf2f(hh));
        vh[e] = (short)hh; vl[e] = (short)ll;
    }
    size_t o = (size_t)h * NN * NN + ((size_t)jt * 32 + kt) * 512 + lane * 8;
    *(bf16x8*)(tph + o) = vh;
    *(bf16x8*)(tpl + o) = vl;
}

// ---------------------------------------------------------------------------
// wsq[row] = sum_k emb[row][k]^2  (fp32 exact)
// ---------------------------------------------------------------------------
__global__ __launch_bounds__(256) void k_wsq(const float* __restrict__ emb,
                                             float* __restrict__ wsq) {
    int wave = threadIdx.x >> 6;
    int lane = threadIdx.x & 63;
    int row  = blockIdx.x * 4 + wave;
    const float* w = emb + (size_t)row * DHD;
    float4 v = *(const float4*)(w + lane * 4);
    float s = v.x * v.x + v.y * v.y + v.z * v.z + v.w * v.w;
    for (int off = 32; off; off >>= 1) s += __shfl_down(s, off);
    if (lane == 0) wsq[row] = s;
}

// ---------------------------------------------------------------------------
// Fragment-direct MFMA logits (numerics identical to round 4/5). No LDS, no
// barriers: every operand is pre-packed, each wave loads its fragments with
// one 16B global load each. TILE 64x64, wave = 32x32 (2x2 frags).
// grid (NN/64, BB/64).
// ---------------------------------------------------------------------------
template <int HASPREV>
__global__ __launch_bounds__(256) void k_logits_frag(
        const u16* __restrict__ Xph, const u16* __restrict__ Xpm, const u16* __restrict__ Xpl,
        const u16* __restrict__ Wph, const u16* __restrict__ Wpm, const u16* __restrict__ Wpl,
        const float* __restrict__ wsq,
        const u16* __restrict__ Pph, const u16* __restrict__ Ppl,
        const u16* __restrict__ Tph, const u16* __restrict__ Tpl,
        float* __restrict__ L) {
    const int t = threadIdx.x;
    const int lane = t & 63, wid = t >> 6;
    const int wmi = wid >> 1, wn = wid & 1;
    const int q = lane >> 4, mr = lane & 15;
    const int j0 = blockIdx.x * 64, i0 = blockIdx.y * 64;
    const int it0 = (i0 >> 4) + wmi * 2;
    const int jt0 = (j0 >> 4) + wn * 2;
    const int lo = lane * 8;

    f32x4 zero = {0.f, 0.f, 0.f, 0.f};
    f32x4 s[2][2], acc2[2][2];
#pragma unroll
    for (int mt = 0; mt < 2; mt++)
#pragma unroll
        for (int nt = 0; nt < 2; nt++) { s[mt][nt] = zero; acc2[mt][nt] = zero; }

    // ---- phase 1: split(2x) . split(w), K = DHD, TK = 8 ----
    {
        const u16 *ahp[2], *amp[2], *alp[2], *bhp[2], *bmp[2], *blp[2];
#pragma unroll
        for (int mt = 0; mt < 2; mt++) {
            size_t b = (size_t)(it0 + mt) * 8 * 512 + lo;
            ahp[mt] = Xph + b; amp[mt] = Xpm + b; alp[mt] = Xpl + b;
        }
#pragma unroll
        for (int nt = 0; nt < 2; nt++) {
            size_t b = (size_t)(jt0 + nt) * 8 * 512 + lo;
            bhp[nt] = Wph + b; bmp[nt] = Wpm + b; blp[nt] = Wpl + b;
        }
#pragma unroll 2
        for (int kt = 0; kt < 8; kt++) {
            bf16x8 ah[2], am[2], al[2], bh[2], bm[2], bl[2];
#pragma unroll
            for (int mt = 0; mt < 2; mt++) {
                ah[mt] = *(const bf16x8*)(ahp[mt] + kt * 512);
                am[mt] = *(const bf16x8*)(amp[mt] + kt * 512);
                al[mt] = *(const bf16x8*)(alp[mt] + kt * 512);
            }
#pragma unroll
            for (int nt = 0; nt < 2; nt++) {
                bh[nt] = *(const bf16x8*)(bhp[nt] + kt * 512);
                bm[nt] = *(const bf16x8*)(bmp[nt] + kt * 512);
                bl[nt] = *(const bf16x8*)(blp[nt] + kt * 512);
            }
#pragma unroll
            for (int mt = 0; mt < 2; mt++)
#pragma unroll
                for (int nt = 0; nt < 2; nt++) {
                    f32x4 fresh = MFMA(ah[mt], bh[nt], zero);   // dominant term
                    s[mt][nt] += fresh;                         // VALU merge
                    acc2[mt][nt] = MFMA(ah[mt], bm[nt], acc2[mt][nt]);
                    acc2[mt][nt] = MFMA(am[mt], bh[nt], acc2[mt][nt]);
                    acc2[mt][nt] = MFMA(ah[mt], bl[nt], acc2[mt][nt]);
                    acc2[mt][nt] = MFMA(am[mt], bm[nt], acc2[mt][nt]);
                    acc2[mt][nt] = MFMA(al[mt], bh[nt], acc2[mt][nt]);
                }
        }
    }

    // ---- phase 2: split(P) . split(T)^T, K = NN, TK = 32 ----
    if (HASPREV) {
        const u16 *ahp[2], *alp[2], *bhp[2], *blp[2];
#pragma unroll
        for (int mt = 0; mt < 2; mt++) {
            size_t b = (size_t)(it0 + mt) * 32 * 512 + lo;
            ahp[mt] = Pph + b; alp[mt] = Ppl + b;
        }
#pragma unroll
        for (int nt = 0; nt < 2; nt++) {
            size_t b = (size_t)(jt0 + nt) * 32 * 512 + lo;
            bhp[nt] = Tph + b; blp[nt] = Tpl + b;
        }
#pragma unroll 2
        for (int kt = 0; kt < 32; kt++) {
            bf16x8 ah[2], al[2], bh[2], bl[2];
#pragma unroll
            for (int mt = 0; mt < 2; mt++) {
                ah[mt] = *(const bf16x8*)(ahp[mt] + kt * 512);
                al[mt] = *(const bf16x8*)(alp[mt] + kt * 512);
            }
#pragma unroll
            for (int nt = 0; nt < 2; nt++) {
                bh[nt] = *(const bf16x8*)(bhp[nt] + kt * 512);
                bl[nt] = *(const bf16x8*)(blp[nt] + kt * 512);
            }
#pragma unroll
            for (int mt = 0; mt < 2; mt++)
#pragma unroll
                for (int nt = 0; nt < 2; nt++) {
                    acc2[mt][nt] = MFMA(ah[mt], bh[nt], acc2[mt][nt]);
                    acc2[mt][nt] = MFMA(ah[mt], bl[nt], acc2[mt][nt]);
                    acc2[mt][nt] = MFMA(al[mt], bh[nt], acc2[mt][nt]);
                }
        }
    }

    float wq[2];
#pragma unroll
    for (int nt = 0; nt < 2; nt++) wq[nt] = wsq[j0 + wn * 32 + nt * 16 + mr];
#pragma unroll
    for (int mt = 0; mt < 2; mt++)
#pragma unroll
        for (int nt = 0; nt < 2; nt++)
#pragma unroll
            for (int r = 0; r < 4; r++) {
                int gi = i0 + wmi * 32 + mt * 16 + q * 4 + r;
                int gj = j0 + wn * 32 + nt * 16 + mr;
                L[(size_t)gi * NN + gj] = (s[mt][nt][r] + acc2[mt][nt][r]) - wq[nt];
            }
}

// ---------------------------------------------------------------------------
// softmax row of N=1024, argmax -> codes, writes split-bf16 probs [B][N]
// ---------------------------------------------------------------------------
__global__ __launch_bounds__(256) void k_softmax(const float* __restrict__ L,
                                                 u16* __restrict__ Ph,
                                                 u16* __restrict__ Pl,
                                                 float* __restrict__ codes,
                                                 int h) {
    __shared__ float smax[256];
    __shared__ int   sidx[256];
    const int i = blockIdx.x;
    const int t = threadIdx.x;
    const float* row = L + (size_t)i * NN;

    float v[4];
    float m = -INFINITY;
    int   mi = 0;
#pragma unroll
    for (int q4 = 0; q4 < 4; q4++) {
        int j = q4 * 256 + t;
        v[q4] = row[j];
        if (v[q4] > m) { m = v[q4]; mi = j; }
    }
    smax[t] = m; sidx[t] = mi;
    __syncthreads();
    for (int s = 128; s; s >>= 1) {
        if (t < s) {
            float o = smax[t + s]; int oi = sidx[t + s];
            if (o > smax[t] || (o == smax[t] && oi < sidx[t])) { smax[t] = o; sidx[t] = oi; }
        }
        __syncthreads();
    }
    m = smax[0];
    int code = sidx[0];
    __syncthreads();

    float s = 0.f;
#pragma unroll
    for (int q4 = 0; q4 < 4; q4++) { v[q4] = expf(v[q4] - m); s += v[q4]; }
    smax[t] = s;
    __syncthreads();
    for (int ss = 128; ss; ss >>= 1) {
        if (t < ss) smax[t] += smax[t + ss];
        __syncthreads();
    }
    float inv = 1.0f / smax[0];
#pragma unroll
    for (int q4 = 0; q4 < 4; q4++) {
        float pv = v[q4] * inv;
        u16 hb = f2bf(pv);
        Ph[(size_t)i * NN + q4 * 256 + t] = hb;
        Pl[(size_t)i * NN + q4 * 256 + t] = f2bf(pv - bf2f(hb));
    }
    if (t == 0) codes[(size_t)i * HH + h] = (float)code;
}

// ---------------------------------------------------------------------------
// pack P -> Pp (A-layout rows=B, K=N, TK=32). Direct reads, no LDS. grid 2048.
// ---------------------------------------------------------------------------
__global__ __launch_bounds__(256) void k_packP(const u16* __restrict__ Ph,
        const u16* __restrict__ Pl, u16* __restrict__ Pph, u16* __restrict__ Ppl) {
    const int t = threadIdx.x, lane = t & 63, wid = t >> 6;
    const int q = lane >> 4, mr = lane & 15;
    int fid = blockIdx.x * 4 + wid;
    int kt = fid & 31, it = fid >> 5;
    size_t si = (size_t)(it * 16 + mr) * NN + kt * 32 + q * 8;
    bf16x8 vh = *(const bf16x8*)(Ph + si);
    bf16x8 vl = *(const bf16x8*)(Pl + si);
    size_t o = ((size_t)it * 32 + kt) * 512 + lane * 8;
    *(bf16x8*)(Pph + o) = vh;
    *(bf16x8*)(Ppl + o) = vl;
}

// ---------------------------------------------------------------------------
// pack P^T -> PTp (A-layout rows=N, K=B, TK=128). LDS transpose.
// grid (NN/64, BB/64).
// ---------------------------------------------------------------------------
__global__ __launch_bounds__(256) void k_packPT(const u16* __restrict__ Ph,
        const u16* __restrict__ Pl, u16* __restrict__ PTph, u16* __restrict__ PTpl) {
    __shared__ u16 U[64][72];
    const int t = threadIdx.x, lane = t & 63, wid = t >> 6;
    const int q = lane >> 4, mr = lane & 15;
    const int j0 = blockIdx.x * 64, i0 = blockIdx.y * 64;
    for (int pass = 0; pass < 2; pass++) {
        const u16* src = pass ? Pl : Ph;
        u16* dst = pass ? PTpl : PTph;
        if (pass) __syncthreads();
#pragma unroll
        for (int rep = 0; rep < 2; rep++) {
            int id = t + 256 * rep;
            int row = id >> 3, c8 = (id & 7) * 8;
            *(bf16x8*)&U[row][c8] = *(const bf16x8*)(src + (size_t)(i0 + row) * NN + j0 + c8);
        }
        __syncthreads();
        for (int f = wid; f < 8; f += 4) {
            int a = f >> 1, b = f & 1;
            bf16x8 v;
#pragma unroll
            for (int e = 0; e < 8; e++) v[e] = (short)U[b * 32 + q * 8 + e][16 * a + mr];
            size_t o = ((size_t)((j0 >> 4) + a) * 128 + ((i0 >> 5) + b)) * 512 + lane * 8;
            *(bf16x8*)(dst + o) = v;
        }
    }
}

// ---------------------------------------------------------------------------
// colsum[j] += slab sum of (Phi+Plo)
// ---------------------------------------------------------------------------
__global__ __launch_bounds__(256) void k_colsum(const u16* __restrict__ Ph,
                                                const u16* __restrict__ Pl,
                                                float* __restrict__ colsum) {
    int j  = blockIdx.x * 256 + threadIdx.x;
    int i0 = blockIdx.y * 256;
    float s = 0.f;
    for (int i = i0; i < i0 + 256; i++)
        s += bf2f(Ph[(size_t)i * NN + j]) + bf2f(Pl[(size_t)i * NN + j]);
    atomicAdd(&colsum[j], s);
}

// ---------------------------------------------------------------------------
// csn[j] = (cs[j]+eps)/(n+N*eps)*n
// ---------------------------------------------------------------------------
__global__ __launch_bounds__(1024) void k_cs(const float* __restrict__ cluster_size,
                                             const float* __restrict__ colsum,
                                             float* __restrict__ csn, int h) {
    __shared__ float red[1024];
    int j = threadIdx.x;
    float cs = cluster_size[h * NN + j] * DECAY + OMD * colsum[j];
    red[j] = cs;
    __syncthreads();
    for (int s = 512; s; s >>= 1) {
        if (j < s) red[j] += red[j + s];
        __syncthreads();
    }
    float n = red[0];
    csn[j] = (cs + EPSV) / (n + NN * EPSV) * n;
}

// ---------------------------------------------------------------------------
// dw partial: fragment-direct. A = PTp (rows=N, K=B, TK=128), B = XTp per head.
// TILE 64x64, grid (DHD/64, NN/64, 16 i-slabs of 256). No LDS/barriers.
// ---------------------------------------------------------------------------
__global__ __launch_bounds__(256) void k_dw_frag(
        const u16* __restrict__ PTph, const u16* __restrict__ PTpl,
        const u16* __restrict__ XTph, const u16* __restrict__ XTpl,
        float* __restrict__ partial) {
    const int t = threadIdx.x;
    const int lane = t & 63, wid = t >> 6;
    const int wmi = wid >> 1, wn = wid & 1;
    const int q = lane >> 4, mr = lane & 15;
    const int kd0 = blockIdx.x * 64, j0 = blockIdx.y * 64;
    const int z = blockIdx.z;
    const int jt0 = (j0 >> 4) + wmi * 2;
    const int kdt0 = (kd0 >> 4) + wn * 2;
    const int lo = lane * 8;

    f32x4 zero = {0.f, 0.f, 0.f, 0.f};
    f32x4 acc[2][2];
#pragma unroll
    for (int mt = 0; mt < 2; mt++)
#pragma unroll
        for (int nt = 0; nt < 2; nt++) acc[mt][nt] = zero;

    const u16 *ahp[2], *alp[2], *bhp[2], *blp[2];
#pragma unroll
    for (int mt = 0; mt < 2; mt++) {
        size_t b = ((size_t)(jt0 + mt) * 128 + z * 8) * 512 + lo;
        ahp[mt] = PTph + b; alp[mt] = PTpl + b;
    }
#pragma unroll
    for (int nt = 0; nt < 2; nt++) {
        size_t b = ((size_t)(kdt0 + nt) * 128 + z * 8) * 512 + lo;
        bhp[nt] = XTph + b; blp[nt] = XTpl + b;
    }
#pragma unroll 2
    for (int kt = 0; kt < 8; kt++) {
        bf16x8 ah[2], al[2], bh[2], bl[2];
#pragma unroll
        for (int mt = 0; mt < 2; mt++) {
            ah[mt] = *(const bf16x8*)(ahp[mt] + kt * 512);
            al[mt] = *(const bf16x8*)(alp[mt] + kt * 512);
        }
#pragma unroll
        for (int nt = 0; nt < 2; nt++) {
            bh[nt] = *(const bf16x8*)(bhp[nt] + kt * 512);
            bl[nt] = *(const bf16x8*)(blp[nt] + kt * 512);
        }
#pragma unroll
        for (int mt = 0; mt < 2; mt++)
#pragma unroll
            for (int nt = 0; nt < 2; nt++) {
                acc[mt][nt] = MFMA(ah[mt], bh[nt], acc[mt][nt]);
                acc[mt][nt] = MFMA(ah[mt], bl[nt], acc[mt][nt]);
                acc[mt][nt] = MFMA(al[mt], bh[nt], acc[mt][nt]);
            }
    }
#pragma unroll
    for (int mt = 0; mt < 2; mt++)
#pragma unroll
        for (int nt = 0; nt < 2; nt++)
#pragma unroll
            for (int r = 0; r < 4; r++) {
                int gj = j0 + wmi * 32 + mt * 16 + q * 4 + r;
                int gk = kd0 + wn * 32 + nt * 16 + mr;
                atomicAdd(&partial[(size_t)gj * DHD + gk], acc[mt][nt][r]);
            }
}

// ---------------------------------------------------------------------------
// neww epilogue: NWp = packed B-layout (rows=DHD, K=N, TK=32) of
// (ema*DECAY + OMD*partial)/csn, 2-level split. grid (NN/64, DHD/64).
// ---------------------------------------------------------------------------
__global__ __launch_bounds__(256) void k_neww_ep(const float* __restrict__ partial,
        const float* __restrict__ ema, const float* __restrict__ csn,
        u16* __restrict__ NWph, u16* __restrict__ NWpl) {
    __shared__ float T[64][68];
    const int t = threadIdx.x, lane = t & 63, wid = t >> 6;
    const int q = lane >> 4, mr = lane & 15;
    const int j0 = blockIdx.x * 64, kd0 = blockIdx.y * 64;
#pragma unroll
    for (int rep = 0; rep < 4; rep++) {
        int id = t + 256 * rep;
        int jr = id >> 4, c4 = (id & 15) * 4;
        float4 pp = *(const float4*)(partial + (size_t)(j0 + jr) * DHD + kd0 + c4);
        float4 ee = *(const float4*)(ema + (size_t)(j0 + jr) * DHD + kd0 + c4);
        float ic = 1.0f / csn[j0 + jr];
        float4 v;
        v.x = (ee.x * DECAY + OMD * pp.x) * ic;
        v.y = (ee.y * DECAY + OMD * pp.y) * ic;
        v.z = (ee.z * DECAY + OMD * pp.z) * ic;
        v.w = (ee.w * DECAY + OMD * pp.w) * ic;
        *(float4*)&T[jr][c4] = v;
    }
    __syncthreads();
    for (int f = wid; f < 8; f += 4) {
        int a = f >> 1, b = f & 1;   // a: kd row-tile, b: j k-tile
        bf16x8 vh, vl;
#pragma unroll
        for (int e = 0; e < 8; e++) {
            float x = T[b * 32 + q * 8 + e][16 * a + mr];
            u16 hh = f2bf(x);
            u16 ll = f2bf(x - bf2f(hh));
            vh[e] = (short)hh; vl[e] = (short)ll;
        }
        size_t o = ((size_t)((kd0 >> 4) + a) * 32 + ((j0 >> 5) + b)) * 512 + lane * 8;
        *(bf16x8*)(NWph + o) = vh;
        *(bf16x8*)(NWpl + o) = vl;
    }
}

// ---------------------------------------------------------------------------
// quant: fragment-direct. A = Pp (rows=B, K=N, TK=32), B = NWp.
// TILE 64x64, grid (DHD/64, BB/64, 4 j-slabs of 256). Atomic into d_out.
// ---------------------------------------------------------------------------
__global__ __launch_bounds__(256) void k_quant_frag(
        const u16* __restrict__ Pph, const u16* __restrict__ Ppl,
        const u16* __restrict__ NWph, const u16* __restrict__ NWpl,
        float* __restrict__ outq, int h) {
    const int t = threadIdx.x;
    const int lane = t & 63, wid = t >> 6;
    const int wmi = wid >> 1, wn = wid & 1;
    const int q = lane >> 4, mr = lane & 15;
    const int kd0 = blockIdx.x * 64, i0 = blockIdx.y * 64;
    const int z = blockIdx.z;
    const int it0 = (i0 >> 4) + wmi * 2;
    const int kdt0 = (kd0 >> 4) + wn * 2;
    const int lo = lane * 8;

    f32x4 zero = {0.f, 0.f, 0.f, 0.f};
    f32x4 acc[2][2];
#pragma unroll
    for (int mt = 0; mt < 2; mt++)
#pragma unroll
        for (int nt = 0; nt < 2; nt++) acc[mt][nt] = zero;

    const u16 *ahp[2], *alp[2], *bhp[2], *blp[2];
#pragma unroll
    for (int mt = 0; mt < 2; mt++) {
        size_t b = ((size_t)(it0 + mt) * 32 + z * 8) * 512 + lo;
        ahp[mt] = Pph + b; alp[mt] = Ppl + b;
    }
#pragma unroll
    for (int nt = 0; nt < 2; nt++) {
        size_t b = ((size_t)(kdt0 + nt) * 32 + z * 8) * 512 + lo;
        bhp[nt] = NWph + b; blp[nt] = NWpl + b;
    }
#pragma unroll 2
    for (int kt = 0; kt < 8; kt++) {
        bf16x8 ah[2], al[2], bh[2], bl[2];
#pragma unroll
        for (int mt = 0; mt < 2; mt++) {
            ah[mt] = *(const bf16x8*)(ahp[mt] + kt * 512);
            al[mt] = *(const bf16x8*)(alp[mt] + kt * 512);
        }
#pragma unroll
        for (int nt = 0; nt < 2; nt++) {
            bh[nt] = *(const bf16x8*)(bhp[nt] + kt * 512);
            bl[nt] = *(const bf16x8*)(blp[nt] + kt * 512);
        }
#pragma unroll
        for (int mt = 0; mt < 2; mt++)
#pragma unroll
            for (int nt = 0; nt < 2; nt++) {
                acc[mt][nt] = MFMA(ah[mt], bh[nt], acc[mt][nt]);
                acc[mt][nt] = MFMA(ah[mt], bl[nt], acc[mt][nt]);
                acc[mt][nt] = MFMA(al[mt], bh[nt], acc[mt][nt]);
            }
    }
#pragma unroll
    for (int mt = 0; mt < 2; mt++)
#pragma unroll
        for (int nt = 0; nt < 2; nt++)
#pragma unroll
            for (int r = 0; r < 4; r++) {
                int gi = i0 + wmi * 32 + mt * 16 + q * 4 + r;
                int gk = kd0 + wn * 32 + nt * 16 + mr;
                atomicAdd(&outq[(size_t)gi * XLD + h * DHD + gk], acc[mt][nt][r]);
            }
}

// ---------------------------------------------------------------------------
// loss[i] = 1.25 * mean_k (q[i][k] - x[i][k])^2
// ---------------------------------------------------------------------------
__global__ __launch_bounds__(256) void k_loss(const float* __restrict__ x,
                                              const float* __restrict__ qv,
                                              float* __restrict__ loss) {
    __shared__ float red[256];
    const int i = blockIdx.x, t = threadIdx.x;
    const float* xr = x + (size_t)i * XLD;
    const float* qr = qv + (size_t)i * XLD;
    float s = 0.f;
#pragma unroll
    for (int q4 = 0; q4 < 4; q4++) {
        int k = q4 * 256 + t;
        float d = qr[k] - xr[k];
        s += d * d;
    }
    red[t] = s;
    __syncthreads();
    for (int ss = 128; ss; ss >>= 1) {
        if (t < ss) red[t] += red[t + ss];
        __syncthreads();
    }
    if (t == 0) loss[i] = 1.25f * red[0] * (1.0f / 1024.0f);
}

// ---------------------------------------------------------------------------
extern "C" void kernel_launch(void* const* d_in, const int* in_sizes, int n_in,
                              void* d_out, int out_size, void* d_ws, size_t ws_size,
                              hipStream_t stream) {
    const float* inputs = (const float*)d_in[0];
    const float* emb    = (const float*)d_in[1];
    const float* ema    = (const float*)d_in[2];
    const float* csz    = (const float*)d_in[3];
    const float* trans  = (const float*)d_in[4];

    float* out   = (float*)d_out;
    float* loss  = out;
    float* quant = out + BB;
    float* codes = out + BB + (size_t)BB * XLD;

    char* p = (char*)d_ws;
    float* L = (float*)p; p += (size_t)BB * NN * 4;   // 16MB; PTp aliased here
    u16* PTph = (u16*)L;
    u16* PTpl = PTph + (size_t)BB * NN;
    u16* Ph   = (u16*)p; p += (size_t)BB * NN * 2;
    u16* Pl   = (u16*)p; p += (size_t)BB * NN * 2;
    u16* Pph  = (u16*)p; p += (size_t)BB * NN * 2;
    u16* Ppl  = (u16*)p; p += (size_t)BB * NN * 2;
    u16* Xph  = (u16*)p; p += (size_t)BB * XLD * 2;
    u16* Xpm  = (u16*)p; p += (size_t)BB * XLD * 2;
    u16* Xpl  = (u16*)p; p += (size_t)BB * XLD * 2;
    u16* XTph = (u16*)p; p += (size_t)XLD * BB * 2;
    u16* XTpl = (u16*)p; p += (size_t)XLD * BB * 2;
    u16* Wph  = (u16*)p; p += (size_t)HH * NN * DHD * 2;
    u16* Wpm  = (u16*)p; p += (size_t)HH * NN * DHD * 2;
    u16* Wpl  = (u16*)p; p += (size_t)HH * NN * DHD * 2;
    u16* Tph  = (u16*)p; p += (size_t)HH * NN * NN * 2;
    u16* Tpl  = (u16*)p; p += (size_t)HH * NN * NN * 2;
    u16* NWph = (u16*)p; p += (size_t)DHD * NN * 2;
    u16* NWpl = (u16*)p; p += (size_t)DHD * NN * 2;
    float* wsq    = (float*)p; p += (size_t)HH * NN * 4;
    float* colsum = (float*)p; p += NN * 4;
    float* csn    = (float*)p; p += NN * 4;
    float* partial = (float*)p; p += (size_t)NN * DHD * 4;

    k_prep_x<<<dim3(XLD / 64, BB / 64), 256, 0, stream>>>(inputs, Xph, Xpm, Xpl, XTph, XTpl);
    k_prep_w<<<HH * 64 * 8 / 4, 256, 0, stream>>>(emb, Wph, Wpm, Wpl);
    k_prep_t<<<HH * 64 * 32 / 4, 256, 0, stream>>>(trans, Tph, Tpl);
    k_wsq<<<HH * NN / 4, 256, 0, stream>>>(emb, wsq);
    hipMemsetAsync(quant, 0, (size_t)BB * XLD * 4, stream);

    for (int h = 0; h < HH; h++) {
        const u16* Xhh = Xph + (size_t)h * BB * DHD;
        const u16* Xmh = Xpm + (size_t)h * BB * DHD;
        const u16* Xlh = Xpl + (size_t)h * BB * DHD;
        const u16* Whh = Wph + (size_t)h * NN * DHD;
        const u16* Wmh = Wpm + (size_t)h * NN * DHD;
        const u16* Wlh = Wpl + (size_t)h * NN * DHD;
        if (h == 0)
            k_logits_frag<0><<<dim3(NN / 64, BB / 64), 256, 0, stream>>>(
                Xhh, Xmh, Xlh, Whh, Wmh, Wlh, wsq + h * NN,
                nullptr, nullptr, nullptr, nullptr, L);
        else
            k_logits_frag<1><<<dim3(NN / 64, BB / 64), 256, 0, stream>>>(
                Xhh, Xmh, Xlh, Whh, Wmh, Wlh, wsq + h * NN,
                Pph, Ppl, Tph + (size_t)h * NN * NN, Tpl + (size_t)h * NN * NN, L);

        k_softmax<<<BB, 256, 0, stream>>>(L, Ph, Pl, codes, h);
        k_packP<<<BB / 16 * NN / 32 / 4, 256, 0, stream>>>(Ph, Pl, Pph, Ppl);
        k_packPT<<<dim3(NN / 64, BB / 64), 256, 0, stream>>>(Ph, Pl, PTph, PTpl);

        hipMemsetAsync(colsum, 0, NN * sizeof(float), stream);
        k_colsum<<<dim3(NN / 256, 16), 256, 0, stream>>>(Ph, Pl, colsum);
        k_cs<<<1, NN, 0, stream>>>(csz, colsum, csn, h);

        hipMemsetAsync(partial, 0, (size_t)NN * DHD * sizeof(float), stream);
        k_dw_frag<<<dim3(DHD / 64, NN / 64, 16), 256, 0, stream>>>(
            PTph, PTpl, XTph + (size_t)h * DHD * BB, XTpl + (size_t)h * DHD * BB, partial);
        k_neww_ep<<<dim3(NN / 64, DHD / 64), 256, 0, stream>>>(
            partial, ema + (size_t)h * NN * DHD, csn, NWph, NWpl);

        k_quant_frag<<<dim3(DHD / 64, BB / 64, 4), 256, 0, stream>>>(
            Pph, Ppl, NWph, NWpl, quant, h);
    }

    k_loss<<<BB, 256, 0, stream>>>(inputs, quant, loss);
}

// Round 7
// 598.687 us; speedup vs baseline: 1.1509x; 1.1184x over previous
//
#include <hip/hip_runtime.h>
#include <hip/hip_bf16.h>
#include <math.h>

#define BB 4096
#define HH 4
#define NN 1024
#define DHD 256
#define XLD 1024   // H*DH
#define DECAY 0.99f
#define OMD 0.01f
#define EPSV 1e-5f

typedef __attribute__((ext_vector_type(8))) short bf16x8;
typedef __attribute__((ext_vector_type(4))) float f32x4;
typedef unsigned short u16;

#define MFMA(a, b, c) __builtin_amdgcn_mfma_f32_16x16x32_bf16((a), (b), (c), 0, 0, 0)

// Fragment-packed layout: matrix [R][K] -> tiles (rt = r>>4, kt = k>>5), frag of
// 512 u16 at ((rt*TK + kt)*512); within frag lane = (r&15) | (((k>>3)&3)<<4),
// elements k = kt*32 + (lane>>4)*8 + j at offset lane*8+j. One 16B load/wave.

static __device__ __forceinline__ u16 f2bf(float x) {
    union { __hip_bfloat16 b; u16 u; } c; c.b = __float2bfloat16(x); return c.u;
}
static __device__ __forceinline__ float bf2f(u16 u) {
    union { __hip_bfloat16 b; u16 u; } c; c.u = u; return __bfloat162float(c.b);
}
static __device__ __forceinline__ void split3(float x, u16& h, u16& m, u16& l) {
    h = f2bf(x);
    float r = x - bf2f(h);
    m = f2bf(r);
    float r2 = r - bf2f(m);
    l = f2bf(r2);
}

// ---------------------------------------------------------------------------
// prep X: Xp (3-level split of 2x, A-layout per head TK=8) and XTp (2-level
// split of x, B-layout per head TK=128). grid (XLD/64, BB/64).
// ---------------------------------------------------------------------------
__global__ __launch_bounds__(256) void k_prep_x(const float* __restrict__ in,
        u16* __restrict__ xph, u16* __restrict__ xpm, u16* __restrict__ xpl,
        u16* __restrict__ xtph, u16* __restrict__ xtpl) {
    __shared__ float T[64][68];
    const int t = threadIdx.x, lane = t & 63, wid = t >> 6;
    const int q = lane >> 4, mr = lane & 15;
    const int c0 = blockIdx.x * 64, i0 = blockIdx.y * 64;
    const int h = c0 >> 8, kl0 = c0 & 255;
#pragma unroll
    for (int rep = 0; rep < 4; rep++) {
        int id = t + 256 * rep;
        int row = id >> 4, c4 = (id & 15) * 4;
        float4 v = *(const float4*)(in + (size_t)(i0 + row) * XLD + c0 + c4);
        *(float4*)&T[row][c4] = v;
    }
    __syncthreads();
    for (int f = wid; f < 8; f += 4) {
        int a = f >> 1, b = f & 1;
        bf16x8 vh, vm, vl;
#pragma unroll
        for (int e = 0; e < 8; e++) {
            float x2 = 2.f * T[16 * a + mr][b * 32 + q * 8 + e];
            u16 hh, mm, ll; split3(x2, hh, mm, ll);
            vh[e] = (short)hh; vm[e] = (short)mm; vl[e] = (short)ll;
        }
        size_t o = (size_t)h * BB * DHD +
                   ((size_t)((i0 >> 4) + a) * 8 + ((kl0 >> 5) + b)) * 512 + lane * 8;
        *(bf16x8*)(xph + o) = vh;
        *(bf16x8*)(xpm + o) = vm;
        *(bf16x8*)(xpl + o) = vl;
    }
    for (int f = wid; f < 8; f += 4) {
        int a = f >> 1, b = f & 1;
        bf16x8 vh, vl;
#pragma unroll
        for (int e = 0; e < 8; e++) {
            float x = T[b * 32 + q * 8 + e][16 * a + mr];
            u16 hh = f2bf(x);
            u16 ll = f2bf(x - bf2f(hh));
            vh[e] = (short)hh; vl[e] = (short)ll;
        }
        size_t o = (size_t)h * DHD * BB +
                   ((size_t)((kl0 >> 4) + a) * 128 + ((i0 >> 5) + b)) * 512 + lane * 8;
        *(bf16x8*)(xtph + o) = vh;
        *(bf16x8*)(xtpl + o) = vl;
    }
}

// ---------------------------------------------------------------------------
// prep W: 3-level split, B-layout per head TK=8. grid 512.
// ---------------------------------------------------------------------------
__global__ __launch_bounds__(256) void k_prep_w(const float* __restrict__ w,
        u16* __restrict__ wph, u16* __restrict__ wpm, u16* __restrict__ wpl) {
    const int t = threadIdx.x, lane = t & 63, wid = t >> 6;
    const int q = lane >> 4, mr = lane & 15;
    int fid = blockIdx.x * 4 + wid;
    int kt = fid & 7, jt = (fid >> 3) & 63, h = fid >> 9;
    const float* src = w + (size_t)(h * NN + jt * 16 + mr) * DHD + kt * 32 + q * 8;
    bf16x8 vh, vm, vl;
#pragma unroll
    for (int e = 0; e < 8; e++) {
        u16 hh, mm, ll; split3(src[e], hh, mm, ll);
        vh[e] = (short)hh; vm[e] = (short)mm; vl[e] = (short)ll;
    }
    size_t o = (size_t)h * NN * DHD + ((size_t)jt * 8 + kt) * 512 + lane * 8;
    *(bf16x8*)(wph + o) = vh;
    *(bf16x8*)(wpm + o) = vm;
    *(bf16x8*)(wpl + o) = vl;
}

// prep T: 2-level split, B-layout per head TK=32. grid 2048.
__global__ __launch_bounds__(256) void k_prep_t(const float* __restrict__ w,
        u16* __restrict__ tph, u16* __restrict__ tpl) {
    const int t = threadIdx.x, lane = t & 63, wid = t >> 6;
    const int q = lane >> 4, mr = lane & 15;
    int fid = blockIdx.x * 4 + wid;
    int kt = fid & 31, jt = (fid >> 5) & 63, h = fid >> 11;
    const float* src = w + (size_t)(h * NN + jt * 16 + mr) * NN + kt * 32 + q * 8;
    bf16x8 vh, vl;
#pragma unroll
    for (int e = 0; e < 8; e++) {
        u16 hh = f2bf(src[e]);
        u16 ll = f2bf(src[e] - bf2f(hh));
        vh[e] = (short)hh; vl[e] = (short)ll;
    }
    size_t o = (size_t)h * NN * NN + ((size_t)jt * 32 + kt) * 512 + lane * 8;
    *(bf16x8*)(tph + o) = vh;
    *(bf16x8*)(tpl + o) = vl;
}

// ---------------------------------------------------------------------------
// wsq[row] = sum_k emb[row][k]^2  (fp32 exact)
// ---------------------------------------------------------------------------
__global__ __launch_bounds__(256) void k_wsq(const float* __restrict__ emb,
                                             float* __restrict__ wsq) {
    int wave = threadIdx.x >> 6;
    int lane = threadIdx.x & 63;
    int row  = blockIdx.x * 4 + wave;
    const float* w = emb + (size_t)row * DHD;
    float4 v = *(const float4*)(w + lane * 4);
    float s = v.x * v.x + v.y * v.y + v.z * v.z + v.w * v.w;
    for (int off = 32; off; off >>= 1) s += __shfl_down(s, off);
    if (lane == 0) wsq[row] = s;
}

// ---------------------------------------------------------------------------
// logits phase 1: split(2x).split(w) (6 terms), K=DHD, TK=8. Writes
// L = s + acc2 - wsq. TILE 64x64, grid (NN/64, BB/64). No LDS/barriers.
// ---------------------------------------------------------------------------
__global__ __launch_bounds__(256) void k_logits_p1(
        const u16* __restrict__ Xph, const u16* __restrict__ Xpm, const u16* __restrict__ Xpl,
        const u16* __restrict__ Wph, const u16* __restrict__ Wpm, const u16* __restrict__ Wpl,
        const float* __restrict__ wsq, float* __restrict__ L) {
    const int t = threadIdx.x;
    const int lane = t & 63, wid = t >> 6;
    const int wmi = wid >> 1, wn = wid & 1;
    const int q = lane >> 4, mr = lane & 15;
    const int j0 = blockIdx.x * 64, i0 = blockIdx.y * 64;
    const int it0 = (i0 >> 4) + wmi * 2;
    const int jt0 = (j0 >> 4) + wn * 2;
    const int lo = lane * 8;

    f32x4 zero = {0.f, 0.f, 0.f, 0.f};
    f32x4 s[2][2], acc2[2][2];
#pragma unroll
    for (int mt = 0; mt < 2; mt++)
#pragma unroll
        for (int nt = 0; nt < 2; nt++) { s[mt][nt] = zero; acc2[mt][nt] = zero; }

    const u16 *ahp[2], *amp[2], *alp[2], *bhp[2], *bmp[2], *blp[2];
#pragma unroll
    for (int mt = 0; mt < 2; mt++) {
        size_t b = (size_t)(it0 + mt) * 8 * 512 + lo;
        ahp[mt] = Xph + b; amp[mt] = Xpm + b; alp[mt] = Xpl + b;
    }
#pragma unroll
    for (int nt = 0; nt < 2; nt++) {
        size_t b = (size_t)(jt0 + nt) * 8 * 512 + lo;
        bhp[nt] = Wph + b; bmp[nt] = Wpm + b; blp[nt] = Wpl + b;
    }
#pragma unroll 2
    for (int kt = 0; kt < 8; kt++) {
        bf16x8 ah[2], am[2], al[2], bh[2], bm[2], bl[2];
#pragma unroll
        for (int mt = 0; mt < 2; mt++) {
            ah[mt] = *(const bf16x8*)(ahp[mt] + kt * 512);
            am[mt] = *(const bf16x8*)(amp[mt] + kt * 512);
            al[mt] = *(const bf16x8*)(alp[mt] + kt * 512);
        }
#pragma unroll
        for (int nt = 0; nt < 2; nt++) {
            bh[nt] = *(const bf16x8*)(bhp[nt] + kt * 512);
            bm[nt] = *(const bf16x8*)(bmp[nt] + kt * 512);
            bl[nt] = *(const bf16x8*)(blp[nt] + kt * 512);
        }
#pragma unroll
        for (int mt = 0; mt < 2; mt++)
#pragma unroll
            for (int nt = 0; nt < 2; nt++) {
                f32x4 fresh = MFMA(ah[mt], bh[nt], zero);   // dominant term
                s[mt][nt] += fresh;                         // VALU merge
                acc2[mt][nt] = MFMA(ah[mt], bm[nt], acc2[mt][nt]);
                acc2[mt][nt] = MFMA(am[mt], bh[nt], acc2[mt][nt]);
                acc2[mt][nt] = MFMA(ah[mt], bl[nt], acc2[mt][nt]);
                acc2[mt][nt] = MFMA(am[mt], bm[nt], acc2[mt][nt]);
                acc2[mt][nt] = MFMA(al[mt], bh[nt], acc2[mt][nt]);
            }
    }

    float wq[2];
#pragma unroll
    for (int nt = 0; nt < 2; nt++) wq[nt] = wsq[j0 + wn * 32 + nt * 16 + mr];
#pragma unroll
    for (int mt = 0; mt < 2; mt++)
#pragma unroll
        for (int nt = 0; nt < 2; nt++)
#pragma unroll
            for (int r = 0; r < 4; r++) {
                int gi = i0 + wmi * 32 + mt * 16 + q * 4 + r;
                int gj = j0 + wn * 32 + nt * 16 + mr;
                L[(size_t)gi * NN + gj] = (s[mt][nt][r] + acc2[mt][nt][r]) - wq[nt];
            }
}

// ---------------------------------------------------------------------------
// logits phase 2: split(P).split(T)^T (3 terms), K=NN, TK=32, split-K kz=2.
// atomicAdds into L (after p1's write). grid (NN/64, BB/64, 2) = 2048 blocks.
// ---------------------------------------------------------------------------
__global__ __launch_bounds__(256) void k_logits_p2(
        const u16* __restrict__ Pph, const u16* __restrict__ Ppl,
        const u16* __restrict__ Tph, const u16* __restrict__ Tpl,
        float* __restrict__ L) {
    const int t = threadIdx.x;
    const int lane = t & 63, wid = t >> 6;
    const int wmi = wid >> 1, wn = wid & 1;
    const int q = lane >> 4, mr = lane & 15;
    const int j0 = blockIdx.x * 64, i0 = blockIdx.y * 64;
    const int kz = blockIdx.z;
    const int it0 = (i0 >> 4) + wmi * 2;
    const int jt0 = (j0 >> 4) + wn * 2;
    const int lo = lane * 8;

    f32x4 zero = {0.f, 0.f, 0.f, 0.f};
    f32x4 acc2[2][2];
#pragma unroll
    for (int mt = 0; mt < 2; mt++)
#pragma unroll
        for (int nt = 0; nt < 2; nt++) acc2[mt][nt] = zero;

    const u16 *ahp[2], *alp[2], *bhp[2], *blp[2];
#pragma unroll
    for (int mt = 0; mt < 2; mt++) {
        size_t b = ((size_t)(it0 + mt) * 32 + kz * 16) * 512 + lo;
        ahp[mt] = Pph + b; alp[mt] = Ppl + b;
    }
#pragma unroll
    for (int nt = 0; nt < 2; nt++) {
        size_t b = ((size_t)(jt0 + nt) * 32 + kz * 16) * 512 + lo;
        bhp[nt] = Tph + b; blp[nt] = Tpl + b;
    }
#pragma unroll 4
    for (int kt = 0; kt < 16; kt++) {
        bf16x8 ah[2], al[2], bh[2], bl[2];
#pragma unroll
        for (int mt = 0; mt < 2; mt++) {
            ah[mt] = *(const bf16x8*)(ahp[mt] + kt * 512);
            al[mt] = *(const bf16x8*)(alp[mt] + kt * 512);
        }
#pragma unroll
        for (int nt = 0; nt < 2; nt++) {
            bh[nt] = *(const bf16x8*)(bhp[nt] + kt * 512);
            bl[nt] = *(const bf16x8*)(blp[nt] + kt * 512);
        }
#pragma unroll
        for (int mt = 0; mt < 2; mt++)
#pragma unroll
            for (int nt = 0; nt < 2; nt++) {
                acc2[mt][nt] = MFMA(ah[mt], bh[nt], acc2[mt][nt]);
                acc2[mt][nt] = MFMA(ah[mt], bl[nt], acc2[mt][nt]);
                acc2[mt][nt] = MFMA(al[mt], bh[nt], acc2[mt][nt]);
            }
    }
#pragma unroll
    for (int mt = 0; mt < 2; mt++)
#pragma unroll
        for (int nt = 0; nt < 2; nt++)
#pragma unroll
            for (int r = 0; r < 4; r++) {
                int gi = i0 + wmi * 32 + mt * 16 + q * 4 + r;
                int gj = j0 + wn * 32 + nt * 16 + mr;
                atomicAdd(&L[(size_t)gi * NN + gj], acc2[mt][nt][r]);
            }
}

// ---------------------------------------------------------------------------
// softmax row of N=1024, argmax -> codes, writes split-bf16 probs [B][N]
// ---------------------------------------------------------------------------
__global__ __launch_bounds__(256) void k_softmax(const float* __restrict__ L,
                                                 u16* __restrict__ Ph,
                                                 u16* __restrict__ Pl,
                                                 float* __restrict__ codes,
                                                 int h) {
    __shared__ float smax[256];
    __shared__ int   sidx[256];
    const int i = blockIdx.x;
    const int t = threadIdx.x;
    const float* row = L + (size_t)i * NN;

    float v[4];
    float m = -INFINITY;
    int   mi = 0;
#pragma unroll
    for (int q4 = 0; q4 < 4; q4++) {
        int j = q4 * 256 + t;
        v[q4] = row[j];
        if (v[q4] > m) { m = v[q4]; mi = j; }
    }
    smax[t] = m; sidx[t] = mi;
    __syncthreads();
    for (int s = 128; s; s >>= 1) {
        if (t < s) {
            float o = smax[t + s]; int oi = sidx[t + s];
            if (o > smax[t] || (o == smax[t] && oi < sidx[t])) { smax[t] = o; sidx[t] = oi; }
        }
        __syncthreads();
    }
    m = smax[0];
    int code = sidx[0];
    __syncthreads();

    float s = 0.f;
#pragma unroll
    for (int q4 = 0; q4 < 4; q4++) { v[q4] = expf(v[q4] - m); s += v[q4]; }
    smax[t] = s;
    __syncthreads();
    for (int ss = 128; ss; ss >>= 1) {
        if (t < ss) smax[t] += smax[t + ss];
        __syncthreads();
    }
    float inv = 1.0f / smax[0];
#pragma unroll
    for (int q4 = 0; q4 < 4; q4++) {
        float pv = v[q4] * inv;
        u16 hb = f2bf(pv);
        Ph[(size_t)i * NN + q4 * 256 + t] = hb;
        Pl[(size_t)i * NN + q4 * 256 + t] = f2bf(pv - bf2f(hb));
    }
    if (t == 0) codes[(size_t)i * HH + h] = (float)code;
}

// ---------------------------------------------------------------------------
// merged pack: reads Ph/Pl tile once -> Pp frags, PTp frags, colsum partial.
// grid (NN/64, BB/64).
// ---------------------------------------------------------------------------
__global__ __launch_bounds__(256) void k_packcs(const u16* __restrict__ Ph,
        const u16* __restrict__ Pl,
        u16* __restrict__ Pph, u16* __restrict__ Ppl,
        u16* __restrict__ PTph, u16* __restrict__ PTpl,
        float* __restrict__ colsum) {
    __shared__ u16 Uh[64][72], Ul[64][72];
    __shared__ float red[4][64];
    const int t = threadIdx.x, lane = t & 63, wid = t >> 6;
    const int q = lane >> 4, mr = lane & 15;
    const int j0 = blockIdx.x * 64, i0 = blockIdx.y * 64;
#pragma unroll
    for (int rep = 0; rep < 2; rep++) {
        int id = t + 256 * rep;
        int row = id >> 3, c8 = (id & 7) * 8;
        size_t si = (size_t)(i0 + row) * NN + j0 + c8;
        *(bf16x8*)&Uh[row][c8] = *(const bf16x8*)(Ph + si);
        *(bf16x8*)&Ul[row][c8] = *(const bf16x8*)(Pl + si);
    }
    __syncthreads();
    // Pp frags (A-layout, rows=B, TK=32)
    for (int f = wid; f < 8; f += 4) {
        int a = f >> 1, b = f & 1;
        bf16x8 vh, vl;
#pragma unroll
        for (int e = 0; e < 8; e++) {
            vh[e] = Uh[a * 16 + mr][b * 32 + q * 8 + e];
            vl[e] = Ul[a * 16 + mr][b * 32 + q * 8 + e];
        }
        size_t o = ((size_t)((i0 >> 4) + a) * 32 + ((j0 >> 5) + b)) * 512 + lane * 8;
        *(bf16x8*)(Pph + o) = vh;
        *(bf16x8*)(Ppl + o) = vl;
    }
    // PTp frags (A-layout, rows=N, TK=128)
    for (int f = wid; f < 8; f += 4) {
        int a = f >> 1, b = f & 1;
        bf16x8 vh, vl;
#pragma unroll
        for (int e = 0; e < 8; e++) {
            vh[e] = Uh[b * 32 + q * 8 + e][a * 16 + mr];
            vl[e] = Ul[b * 32 + q * 8 + e][a * 16 + mr];
        }
        size_t o = ((size_t)((j0 >> 4) + a) * 128 + ((i0 >> 5) + b)) * 512 + lane * 8;
        *(bf16x8*)(PTph + o) = vh;
        *(bf16x8*)(PTpl + o) = vl;
    }
    // colsum partial over this 64-row slab
    int c = t & 63, quarter = t >> 6;
    float s = 0.f;
    for (int r = quarter * 16; r < quarter * 16 + 16; r++)
        s += bf2f((u16)Uh[r][c]) + bf2f((u16)Ul[r][c]);
    red[quarter][c] = s;
    __syncthreads();
    if (t < 64) {
        float tot = red[0][t] + red[1][t] + red[2][t] + red[3][t];
        atomicAdd(&colsum[j0 + t], tot);
    }
}

// ---------------------------------------------------------------------------
// csn[j] = (cs[j]+eps)/(n+N*eps)*n
// ---------------------------------------------------------------------------
__global__ __launch_bounds__(1024) void k_cs(const float* __restrict__ cluster_size,
                                             const float* __restrict__ colsum,
                                             float* __restrict__ csn, int h) {
    __shared__ float red[1024];
    int j = threadIdx.x;
    float cs = cluster_size[h * NN + j] * DECAY + OMD * colsum[j];
    red[j] = cs;
    __syncthreads();
    for (int s = 512; s; s >>= 1) {
        if (j < s) red[j] += red[j + s];
        __syncthreads();
    }
    float n = red[0];
    csn[j] = (cs + EPSV) / (n + NN * EPSV) * n;
}

// ---------------------------------------------------------------------------
// dw: A = PTp, B = XTp. TILE 64x64, grid (DHD/64, NN/64, 16 slabs). Writes
// per-slab buffers (no atomics): partial16[z][j][kd].
// ---------------------------------------------------------------------------
__global__ __launch_bounds__(256) void k_dw_frag(
        const u16* __restrict__ PTph, const u16* __restrict__ PTpl,
        const u16* __restrict__ XTph, const u16* __restrict__ XTpl,
        float* __restrict__ partial16) {
    const int t = threadIdx.x;
    const int lane = t & 63, wid = t >> 6;
    const int wmi = wid >> 1, wn = wid & 1;
    const int q = lane >> 4, mr = lane & 15;
    const int kd0 = blockIdx.x * 64, j0 = blockIdx.y * 64;
    const int z = blockIdx.z;
    const int jt0 = (j0 >> 4) + wmi * 2;
    const int kdt0 = (kd0 >> 4) + wn * 2;
    const int lo = lane * 8;

    f32x4 zero = {0.f, 0.f, 0.f, 0.f};
    f32x4 acc[2][2];
#pragma unroll
    for (int mt = 0; mt < 2; mt++)
#pragma unroll
        for (int nt = 0; nt < 2; nt++) acc[mt][nt] = zero;

    const u16 *ahp[2], *alp[2], *bhp[2], *blp[2];
#pragma unroll
    for (int mt = 0; mt < 2; mt++) {
        size_t b = ((size_t)(jt0 + mt) * 128 + z * 8) * 512 + lo;
        ahp[mt] = PTph + b; alp[mt] = PTpl + b;
    }
#pragma unroll
    for (int nt = 0; nt < 2; nt++) {
        size_t b = ((size_t)(kdt0 + nt) * 128 + z * 8) * 512 + lo;
        bhp[nt] = XTph + b; blp[nt] = XTpl + b;
    }
#pragma unroll 2
    for (int kt = 0; kt < 8; kt++) {
        bf16x8 ah[2], al[2], bh[2], bl[2];
#pragma unroll
        for (int mt = 0; mt < 2; mt++) {
            ah[mt] = *(const bf16x8*)(ahp[mt] + kt * 512);
            al[mt] = *(const bf16x8*)(alp[mt] + kt * 512);
        }
#pragma unroll
        for (int nt = 0; nt < 2; nt++) {
            bh[nt] = *(const bf16x8*)(bhp[nt] + kt * 512);
            bl[nt] = *(const bf16x8*)(blp[nt] + kt * 512);
        }
#pragma unroll
        for (int mt = 0; mt < 2; mt++)
#pragma unroll
            for (int nt = 0; nt < 2; nt++) {
                acc[mt][nt] = MFMA(ah[mt], bh[nt], acc[mt][nt]);
                acc[mt][nt] = MFMA(ah[mt], bl[nt], acc[mt][nt]);
                acc[mt][nt] = MFMA(al[mt], bh[nt], acc[mt][nt]);
            }
    }
    float* dst = partial16 + (size_t)z * NN * DHD;
#pragma unroll
    for (int mt = 0; mt < 2; mt++)
#pragma unroll
        for (int nt = 0; nt < 2; nt++)
#pragma unroll
            for (int r = 0; r < 4; r++) {
                int gj = j0 + wmi * 32 + mt * 16 + q * 4 + r;
                int gk = kd0 + wn * 32 + nt * 16 + mr;
                dst[(size_t)gj * DHD + gk] = acc[mt][nt][r];
            }
}

// ---------------------------------------------------------------------------
// neww epilogue: sum 16 dw slabs, apply ema/decay/csn, emit packed NWp
// (B-layout rows=DHD, K=N, TK=32), 2-level split. grid (NN/64, DHD/64).
// ---------------------------------------------------------------------------
__global__ __launch_bounds__(256) void k_neww_ep(const float* __restrict__ partial16,
        const float* __restrict__ ema, const float* __restrict__ csn,
        u16* __restrict__ NWph, u16* __restrict__ NWpl) {
    __shared__ float T[64][68];
    const int t = threadIdx.x, lane = t & 63, wid = t >> 6;
    const int q = lane >> 4, mr = lane & 15;
    const int j0 = blockIdx.x * 64, kd0 = blockIdx.y * 64;
#pragma unroll
    for (int rep = 0; rep < 4; rep++) {
        int id = t + 256 * rep;
        int jr = id >> 4, c4 = (id & 15) * 4;
        size_t off = (size_t)(j0 + jr) * DHD + kd0 + c4;
        float4 acc = {0.f, 0.f, 0.f, 0.f};
        for (int z = 0; z < 16; z++) {
            float4 pp = *(const float4*)(partial16 + (size_t)z * NN * DHD + off);
            acc.x += pp.x; acc.y += pp.y; acc.z += pp.z; acc.w += pp.w;
        }
        float4 ee = *(const float4*)(ema + off);
        float ic = 1.0f / csn[j0 + jr];
        float4 v;
        v.x = (ee.x * DECAY + OMD * acc.x) * ic;
        v.y = (ee.y * DECAY + OMD * acc.y) * ic;
        v.z = (ee.z * DECAY + OMD * acc.z) * ic;
        v.w = (ee.w * DECAY + OMD * acc.w) * ic;
        *(float4*)&T[jr][c4] = v;
    }
    __syncthreads();
    for (int f = wid; f < 8; f += 4) {
        int a = f >> 1, b = f & 1;   // a: kd row-tile, b: j k-tile
        bf16x8 vh, vl;
#pragma unroll
        for (int e = 0; e < 8; e++) {
            float x = T[b * 32 + q * 8 + e][16 * a + mr];
            u16 hh = f2bf(x);
            u16 ll = f2bf(x - bf2f(hh));
            vh[e] = (short)hh; vl[e] = (short)ll;
        }
        size_t o = ((size_t)((kd0 >> 4) + a) * 32 + ((j0 >> 5) + b)) * 512 + lane * 8;
        *(bf16x8*)(NWph + o) = vh;
        *(bf16x8*)(NWpl + o) = vl;
    }
}

// ---------------------------------------------------------------------------
// quant: A = Pp, B = NWp. TILE 64x64, grid (DHD/64, BB/64, 4 slabs). Writes
// per-slab qacc4[z][i][kd] (no atomics).
// ---------------------------------------------------------------------------
__global__ __launch_bounds__(256) void k_quant_frag(
        const u16* __restrict__ Pph, const u16* __restrict__ Ppl,
        const u16* __restrict__ NWph, const u16* __restrict__ NWpl,
        float* __restrict__ qacc4) {
    const int t = threadIdx.x;
    const int lane = t & 63, wid = t >> 6;
    const int wmi = wid >> 1, wn = wid & 1;
    const int q = lane >> 4, mr = lane & 15;
    const int kd0 = blockIdx.x * 64, i0 = blockIdx.y * 64;
    const int z = blockIdx.z;
    const int it0 = (i0 >> 4) + wmi * 2;
    const int kdt0 = (kd0 >> 4) + wn * 2;
    const int lo = lane * 8;

    f32x4 zero = {0.f, 0.f, 0.f, 0.f};
    f32x4 acc[2][2];
#pragma unroll
    for (int mt = 0; mt < 2; mt++)
#pragma unroll
        for (int nt = 0; nt < 2; nt++) acc[mt][nt] = zero;

    const u16 *ahp[2], *alp[2], *bhp[2], *blp[2];
#pragma unroll
    for (int mt = 0; mt < 2; mt++) {
        size_t b = ((size_t)(it0 + mt) * 32 + z * 8) * 512 + lo;
        ahp[mt] = Pph + b; alp[mt] = Ppl + b;
    }
#pragma unroll
    for (int nt = 0; nt < 2; nt++) {
        size_t b = ((size_t)(kdt0 + nt) * 32 + z * 8) * 512 + lo;
        bhp[nt] = NWph + b; blp[nt] = NWpl + b;
    }
#pragma unroll 2
    for (int kt = 0; kt < 8; kt++) {
        bf16x8 ah[2], al[2], bh[2], bl[2];
#pragma unroll
        for (int mt = 0; mt < 2; mt++) {
            ah[mt] = *(const bf16x8*)(ahp[mt] + kt * 512);
            al[mt] = *(const bf16x8*)(alp[mt] + kt * 512);
        }
#pragma unroll
        for (int nt = 0; nt < 2; nt++) {
            bh[nt] = *(const bf16x8*)(bhp[nt] + kt * 512);
            bl[nt] = *(const bf16x8*)(blp[nt] + kt * 512);
        }
#pragma unroll
        for (int mt = 0; mt < 2; mt++)
#pragma unroll
            for (int nt = 0; nt < 2; nt++) {
                acc[mt][nt] = MFMA(ah[mt], bh[nt], acc[mt][nt]);
                acc[mt][nt] = MFMA(ah[mt], bl[nt], acc[mt][nt]);
                acc[mt][nt] = MFMA(al[mt], bh[nt], acc[mt][nt]);
            }
    }
    float* dst = qacc4 + (size_t)z * BB * DHD;
#pragma unroll
    for (int mt = 0; mt < 2; mt++)
#pragma unroll
        for (int nt = 0; nt < 2; nt++)
#pragma unroll
            for (int r = 0; r < 4; r++) {
                int gi = i0 + wmi * 32 + mt * 16 + q * 4 + r;
                int gk = kd0 + wn * 32 + nt * 16 + mr;
                dst[(size_t)gi * DHD + gk] = acc[mt][nt][r];
            }
}

// quant epilogue: sum 4 slabs -> outq[i][h*DHD+kd]. grid BB*DHD/1024.
__global__ __launch_bounds__(256) void k_quant_ep(const float* __restrict__ qacc4,
        float* __restrict__ outq, int h) {
    int idx4 = (blockIdx.x * 256 + threadIdx.x) * 4;
    int i = idx4 >> 8, kd = idx4 & 255;
    float4 s = {0.f, 0.f, 0.f, 0.f};
#pragma unroll
    for (int z = 0; z < 4; z++) {
        float4 v = *(const float4*)(qacc4 + (size_t)z * BB * DHD + idx4);
        s.x += v.x; s.y += v.y; s.z += v.z; s.w += v.w;
    }
    *(float4*)(outq + (size_t)i * XLD + h * DHD + kd) = s;
}

// ---------------------------------------------------------------------------
// loss[i] = 1.25 * mean_k (q[i][k] - x[i][k])^2
// ---------------------------------------------------------------------------
__global__ __launch_bounds__(256) void k_loss(const float* __restrict__ x,
                                              const float* __restrict__ qv,
                                              float* __restrict__ loss) {
    __shared__ float red[256];
    const int i = blockIdx.x, t = threadIdx.x;
    const float* xr = x + (size_t)i * XLD;
    const float* qr = qv + (size_t)i * XLD;
    float s = 0.f;
#pragma unroll
    for (int q4 = 0; q4 < 4; q4++) {
        int k = q4 * 256 + t;
        float d = qr[k] - xr[k];
        s += d * d;
    }
    red[t] = s;
    __syncthreads();
    for (int ss = 128; ss; ss >>= 1) {
        if (t < ss) red[t] += red[t + ss];
        __syncthreads();
    }
    if (t == 0) loss[i] = 1.25f * red[0] * (1.0f / 1024.0f);
}

// ---------------------------------------------------------------------------
extern "C" void kernel_launch(void* const* d_in, const int* in_sizes, int n_in,
                              void* d_out, int out_size, void* d_ws, size_t ws_size,
                              hipStream_t stream) {
    const float* inputs = (const float*)d_in[0];
    const float* emb    = (const float*)d_in[1];
    const float* ema    = (const float*)d_in[2];
    const float* csz    = (const float*)d_in[3];
    const float* trans  = (const float*)d_in[4];

    float* out   = (float*)d_out;
    float* loss  = out;
    float* quant = out + BB;
    float* codes = out + BB + (size_t)BB * XLD;

    char* p = (char*)d_ws;
    float* L = (float*)p; p += (size_t)BB * NN * 4;   // 16MB; PTp aliased here
    u16* PTph = (u16*)L;
    u16* PTpl = PTph + (size_t)BB * NN;
    u16* Ph   = (u16*)p; p += (size_t)BB * NN * 2;
    u16* Pl   = (u16*)p; p += (size_t)BB * NN * 2;
    u16* Pph  = (u16*)p; p += (size_t)BB * NN * 2;
    u16* Ppl  = (u16*)p; p += (size_t)BB * NN * 2;
    u16* Xph  = (u16*)p; p += (size_t)BB * XLD * 2;
    u16* Xpm  = (u16*)p; p += (size_t)BB * XLD * 2;
    u16* Xpl  = (u16*)p; p += (size_t)BB * XLD * 2;
    u16* XTph = (u16*)p; p += (size_t)XLD * BB * 2;
    u16* XTpl = (u16*)p; p += (size_t)XLD * BB * 2;
    u16* Wph  = (u16*)p; p += (size_t)HH * NN * DHD * 2;
    u16* Wpm  = (u16*)p; p += (size_t)HH * NN * DHD * 2;
    u16* Wpl  = (u16*)p; p += (size_t)HH * NN * DHD * 2;
    u16* Tph  = (u16*)p; p += (size_t)HH * NN * NN * 2;
    u16* Tpl  = (u16*)p; p += (size_t)HH * NN * NN * 2;
    u16* NWph = (u16*)p; p += (size_t)DHD * NN * 2;
    u16* NWpl = (u16*)p; p += (size_t)DHD * NN * 2;
    float* wsq    = (float*)p; p += (size_t)HH * NN * 4;
    float* colsum = (float*)p; p += NN * 4;
    float* csn    = (float*)p; p += NN * 4;
    // shared 16MB scratch: dw slabs (16 x 1MB) then quant slabs (4 x 4MB) —
    // lifetimes are disjoint within a head.
    float* scratch16 = (float*)p; p += (size_t)16 * NN * DHD * 4;

    k_prep_x<<<dim3(XLD / 64, BB / 64), 256, 0, stream>>>(inputs, Xph, Xpm, Xpl, XTph, XTpl);
    k_prep_w<<<HH * 64 * 8 / 4, 256, 0, stream>>>(emb, Wph, Wpm, Wpl);
    k_prep_t<<<HH * 64 * 32 / 4, 256, 0, stream>>>(trans, Tph, Tpl);
    k_wsq<<<HH * NN / 4, 256, 0, stream>>>(emb, wsq);

    for (int h = 0; h < HH; h++) {
        const u16* Xhh = Xph + (size_t)h * BB * DHD;
        const u16* Xmh = Xpm + (size_t)h * BB * DHD;
        const u16* Xlh = Xpl + (size_t)h * BB * DHD;
        const u16* Whh = Wph + (size_t)h * NN * DHD;
        const u16* Wmh = Wpm + (size_t)h * NN * DHD;
        const u16* Wlh = Wpl + (size_t)h * NN * DHD;

        k_logits_p1<<<dim3(NN / 64, BB / 64), 256, 0, stream>>>(
            Xhh, Xmh, Xlh, Whh, Wmh, Wlh, wsq + h * NN, L);
        if (h > 0)
            k_logits_p2<<<dim3(NN / 64, BB / 64, 2), 256, 0, stream>>>(
                Pph, Ppl, Tph + (size_t)h * NN * NN, Tpl + (size_t)h * NN * NN, L);

        k_softmax<<<BB, 256, 0, stream>>>(L, Ph, Pl, codes, h);

        hipMemsetAsync(colsum, 0, NN * sizeof(float), stream);
        k_packcs<<<dim3(NN / 64, BB / 64), 256, 0, stream>>>(
            Ph, Pl, Pph, Ppl, PTph, PTpl, colsum);
        k_cs<<<1, NN, 0, stream>>>(csz, colsum, csn, h);

        k_dw_frag<<<dim3(DHD / 64, NN / 64, 16), 256, 0, stream>>>(
            PTph, PTpl, XTph + (size_t)h * DHD * BB, XTpl + (size_t)h * DHD * BB,
            scratch16);
        k_neww_ep<<<dim3(NN / 64, DHD / 64), 256, 0, stream>>>(
            scratch16, ema + (size_t)h * NN * DHD, csn, NWph, NWpl);

        k_quant_frag<<<dim3(DHD / 64, BB / 64, 4), 256, 0, stream>>>(
            Pph, Ppl, NWph, NWpl, scratch16);
        k_quant_ep<<<BB * DHD / 1024, 256, 0, stream>>>(scratch16, quant, h);
    }

    k_loss<<<BB, 256, 0, stream>>>(inputs, quant, loss);
}